// Round 2
// baseline (522.651 us; speedup 1.0000x reference)
//
#include <hip/hip_runtime.h>
#include <cstdint>
#include <cstddef>

#define SEQ 4096
#define DM  2048
#define NH  16
#define KVH 4
#define HD  128
#define QBLK 128

typedef short bf16_t;
typedef __attribute__((ext_vector_type(8))) short bf16x8;
typedef __attribute__((ext_vector_type(4))) float f32x4;

__device__ __forceinline__ bf16_t f2b(float f) {
  unsigned u = __builtin_bit_cast(unsigned, f);
  u += 0x7fffu + ((u >> 16) & 1u);          // RNE
  return (bf16_t)(u >> 16);
}
__device__ __forceinline__ float b2f(bf16_t s) {
  unsigned u = ((unsigned)(unsigned short)s) << 16;
  return __builtin_bit_cast(float, u);
}

// async global->LDS, 16B per lane. LDS dest is wave-uniform base + lane*16
// (linear); swizzling is done by permuting the per-lane GLOBAL source.
__device__ __forceinline__ void gload_lds16(const void* gsrc, void* ldst) {
  __builtin_amdgcn_global_load_lds(
      (__attribute__((address_space(1))) void*)gsrc,
      (__attribute__((address_space(3))) void*)ldst, 16, 0, 0);
}

// ---------------- cast x -> bf16 ----------------
__global__ void cast_x_bf16(const float* __restrict__ x, bf16_t* __restrict__ xb, int n4) {
  int i = blockIdx.x * 256 + threadIdx.x;
  if (i >= n4) return;
  float4 v = ((const float4*)x)[i];
  union { bf16_t h[4]; unsigned long long u; } o;
  o.h[0] = f2b(v.x); o.h[1] = f2b(v.y); o.h[2] = f2b(v.z); o.h[3] = f2b(v.w);
  ((unsigned long long*)xb)[i] = o.u;
}

// ---------------- W [K][N] fp32 -> Wt [N][K] bf16 ----------------
__global__ void transpose_cast_w(const float* __restrict__ W, bf16_t* __restrict__ Wt,
                                 int K, int N) {
  __shared__ float tile[32][33];
  int k0 = blockIdx.y * 32, n0 = blockIdx.x * 32;
  int tx = threadIdx.x, ty = threadIdx.y;
#pragma unroll
  for (int dy = 0; dy < 32; dy += 8)
    tile[ty + dy][tx] = W[(size_t)(k0 + ty + dy) * N + n0 + tx];
  __syncthreads();
#pragma unroll
  for (int dy = 0; dy < 32; dy += 8)
    Wt[(size_t)(n0 + ty + dy) * K + k0 + tx] = f2b(tile[tx][ty + dy]);
}

// ---------------- RoPE cos/sin table ----------------
__global__ void rope_tab(float* __restrict__ ct, float* __restrict__ st) {
  int i = blockIdx.x * 256 + threadIdx.x;
  if (i >= SEQ * 64) return;
  int t = i >> 6, j = i & 63;
  float invf = expf(-(float)j * (9.210340371976184f / 64.0f)); // 10000^(-j/64)
  float ang = (float)t * invf;
  ct[i] = cosf(ang);
  st[i] = sinf(ang);
}

// ---------------- in-place RoPE on bf16 Q and K ----------------
__global__ void rope_apply(bf16_t* __restrict__ Qb, bf16_t* __restrict__ KVb,
                           const float* __restrict__ ct, const float* __restrict__ st) {
  int i = blockIdx.x * 256 + threadIdx.x;
  const int qtot = SEQ * NH * 64;
  const int tot = qtot + SEQ * KVH * 64;
  if (i >= tot) return;
  bf16_t* base; int t, j;
  if (i < qtot) {
    t = i >> 10; int rem = i & 1023; int hh = rem >> 6; j = rem & 63;
    base = Qb + (size_t)t * DM + hh * HD;
  } else {
    int i2 = i - qtot;
    t = i2 >> 8; int rem = i2 & 255; int hh = rem >> 6; j = rem & 63;
    base = KVb + (size_t)t * 1024 + hh * HD;   // K half = cols 0..511
  }
  float c = ct[t * 64 + j], s = st[t * 64 + j];
  float x0 = b2f(base[j]);
  float x1 = b2f(base[j + 64]);
  base[j]      = f2b(x0 * c - x1 * s);
  base[j + 64] = f2b(x1 * c + x0 * s);
}

// ---------------- V half of KVb [T][1024] -> Vt [512][T] ----------------
__global__ void transpose_v(const bf16_t* __restrict__ KVb, bf16_t* __restrict__ Vt) {
  __shared__ bf16_t tile[32][33];
  int t0 = blockIdx.y * 32, d0 = blockIdx.x * 32;
  int tx = threadIdx.x, ty = threadIdx.y;
#pragma unroll
  for (int dy = 0; dy < 32; dy += 8)
    tile[ty + dy][tx] = KVb[(size_t)(t0 + ty + dy) * 1024 + 512 + d0 + tx];
  __syncthreads();
#pragma unroll
  for (int dy = 0; dy < 32; dy += 8)
    Vt[(size_t)(d0 + ty + dy) * SEQ + t0 + tx] = tile[tx][ty + dy];
}

// ---------------- GEMM: C[M][N] = A[M][K] * Bt[N][K]^T (+bias) ----------------
template <int BIAS>
__global__ __launch_bounds__(256, 2)
void gemm_bt(const bf16_t* __restrict__ A, const bf16_t* __restrict__ Bt,
             void* __restrict__ Cout, const float* __restrict__ bias,
             int M, int N, int K) {
  __shared__ __align__(16) bf16_t ldsA[128 * 64];
  __shared__ __align__(16) bf16_t ldsB[128 * 64];
  const int t = threadIdx.x;
  const int w = t >> 6, l = t & 63;
  const int lg = l >> 4, lr = l & 15;
  const int bm = blockIdx.y, bn = blockIdx.x;
  const int wr = (w >> 1) * 64, wc = (w & 1) * 64;

  f32x4 acc[4][4] = {};

  for (int k0 = 0; k0 < K; k0 += 64) {
    __syncthreads();
#pragma unroll
    for (int i = 0; i < 4; ++i) {
      int idx = i * 256 + t;          // 0..1023, 16B granules
      int row = idx >> 3;             // 8 chunks per 64-col row
      int ch  = (idx & 7) ^ (row & 7);
      gload_lds16(A  + (size_t)(bm * 128 + row) * K + k0 + ch * 8, &ldsA[idx * 8]);
      gload_lds16(Bt + (size_t)(bn * 128 + row) * K + k0 + ch * 8, &ldsB[idx * 8]);
    }
    __syncthreads();
#pragma unroll
    for (int kk = 0; kk < 2; ++kk) {
      bf16x8 af[4], bfr[4];
#pragma unroll
      for (int m = 0; m < 4; ++m) {
        int row = wr + m * 16 + lr;
        int ch = (kk * 4 + lg) ^ (row & 7);
        af[m] = *(const bf16x8*)&ldsA[row * 64 + ch * 8];
      }
#pragma unroll
      for (int n = 0; n < 4; ++n) {
        int row = wc + n * 16 + lr;
        int ch = (kk * 4 + lg) ^ (row & 7);
        bfr[n] = *(const bf16x8*)&ldsB[row * 64 + ch * 8];
      }
#pragma unroll
      for (int m = 0; m < 4; ++m)
#pragma unroll
        for (int n = 0; n < 4; ++n)
          acc[m][n] = __builtin_amdgcn_mfma_f32_16x16x32_bf16(af[m], bfr[n], acc[m][n], 0, 0, 0);
    }
  }

  // D layout: col = lane&15, row = (lane>>4)*4 + r  [measured m89]
  const int row0 = bm * 128 + wr + lg * 4;
  const int col0 = bn * 128 + wc + lr;
  if (BIAS) {
    float* C = (float*)Cout;
#pragma unroll
    for (int n = 0; n < 4; ++n) {
      int col = col0 + n * 16;
      float b = bias[col];
#pragma unroll
      for (int m = 0; m < 4; ++m)
#pragma unroll
        for (int r = 0; r < 4; ++r)
          C[(size_t)(row0 + m * 16 + r) * N + col] = acc[m][n][r] + b;
    }
  } else {
    bf16_t* C = (bf16_t*)Cout;
#pragma unroll
    for (int m = 0; m < 4; ++m)
#pragma unroll
      for (int n = 0; n < 4; ++n) {
        int col = col0 + n * 16;
#pragma unroll
        for (int r = 0; r < 4; ++r)
          C[(size_t)(row0 + m * 16 + r) * N + col] = f2b(acc[m][n][r]);
      }
  }
}

// ---------------- causal flash attention ----------------
// QBLK=128 (4 waves x 32 q-rows), KVBLK=64. K double-buffered in LDS
// (2-phase prefetch, ONE barrier per tile). V read direct from global
// (L2/L3-resident). P via per-wave padded LDS (stride 68, ~2-way banks).
__global__ __launch_bounds__(256, 2)
void attn_fwd(const bf16_t* __restrict__ Qb, const bf16_t* __restrict__ KVb,
              const bf16_t* __restrict__ Vt, bf16_t* __restrict__ ctx) {
  __shared__ __align__(16) bf16_t kt[2][64 * 128];     // K tiles, XOR-swizzled
  __shared__ __align__(16) bf16_t plds[4][2][16 * 68]; // per-wave per-subtile P

  const int t = threadIdx.x;
  const int w = t >> 6, l = t & 63;
  const int lg = l >> 4, lr = l & 15;
  const int h = blockIdx.y, g = h >> 2;
  const int qb = gridDim.x - 1 - blockIdx.x;   // heavy blocks first
  const int q0 = qb * QBLK;
  const int rw = q0 + w * 32;                  // wave's first q-row

  // Q fragments (A-operand: row = lane&15, k = (lane>>4)*8+i)
  bf16x8 qf[2][4];
#pragma unroll
  for (int m = 0; m < 2; ++m)
#pragma unroll
    for (int kk = 0; kk < 4; ++kk)
      qf[m][kk] = *(const bf16x8*)&Qb[(size_t)(rw + m * 16 + lr) * DM + h * HD + kk * 32 + lg * 8];

  f32x4 acc[2][8] = {};
  float m_run[2][4], l_run[2][4];
#pragma unroll
  for (int m = 0; m < 2; ++m)
#pragma unroll
    for (int r = 0; r < 4; ++r) { m_run[m][r] = -1e30f; l_run[m][r] = 0.f; }

  const float sl2e = 0.08838834764831845f * 1.4426950408889634f; // scale*log2(e)

  const bf16_t* ksrc = KVb + g * 128;
  auto stage = [&](int buf, int kvt) {
#pragma unroll
    for (int i = 0; i < 4; ++i) {
      int idx = i * 256 + t;            // 1024 granules: row = idx>>4, chunk = idx&15
      int row = idx >> 4;
      int ch = (idx & 15) ^ (row & 7);
      gload_lds16(ksrc + (size_t)(kvt * 64 + row) * 1024 + ch * 8, &kt[buf][idx * 8]);
    }
  };

  const int nkv = q0 / 64 + 2;
  stage(0, 0);

  for (int kv = 0; kv < nkv; ++kv) {
    const int cur = kv & 1;
    const int kv0 = kv * 64;
    __syncthreads();                    // drains vmcnt: kt[cur] ready
    if (kv + 1 < nkv) stage(cur ^ 1, kv + 1);   // prefetch overlaps compute

    bool act[2];
    act[0] = kv0 <= rw + 15;
    act[1] = kv0 <= rw + 31;

#pragma unroll
    for (int m = 0; m < 2; ++m) {
      if (!act[m]) continue;
      // S = Q K^T  (16 q-rows x 64 keys)
      f32x4 s[4];
#pragma unroll
      for (int n = 0; n < 4; ++n) {
        f32x4 a = {0.f, 0.f, 0.f, 0.f};
        int row = n * 16 + lr;
#pragma unroll
        for (int kk = 0; kk < 4; ++kk) {
          int ch = (kk * 4 + lg) ^ (row & 7);
          bf16x8 kf = *(const bf16x8*)&kt[cur][row * 128 + ch * 8];
          a = __builtin_amdgcn_mfma_f32_16x16x32_bf16(qf[m][kk], kf, a, 0, 0, 0);
        }
        s[n] = a;
      }

      if (kv0 + 63 > rw + m * 16) {     // diagonal-crossing: causal mask
#pragma unroll
        for (int n = 0; n < 4; ++n)
#pragma unroll
          for (int r = 0; r < 4; ++r) {
            int key = kv0 + n * 16 + lr;
            int qrow = rw + m * 16 + lg * 4 + r;
            if (key > qrow) s[n][r] = -1e30f;
          }
      }

      // online softmax (rows live in 16-lane groups)
      float pmax[4];
#pragma unroll
      for (int r = 0; r < 4; ++r)
        pmax[r] = fmaxf(fmaxf(s[0][r], s[1][r]), fmaxf(s[2][r], s[3][r]));
#pragma unroll
      for (int off = 1; off < 16; off <<= 1)
#pragma unroll
        for (int r = 0; r < 4; ++r)
          pmax[r] = fmaxf(pmax[r], __shfl_xor(pmax[r], off, 64));

      float alpha[4], rsum[4];
#pragma unroll
      for (int r = 0; r < 4; ++r) {
        float mn = fmaxf(m_run[m][r], pmax[r]);
        alpha[r] = exp2f((m_run[m][r] - mn) * sl2e);
        m_run[m][r] = mn;
        rsum[r] = 0.f;
      }
#pragma unroll
      for (int n = 0; n < 4; ++n)
#pragma unroll
        for (int r = 0; r < 4; ++r) {
          float p = exp2f((s[n][r] - m_run[m][r]) * sl2e);
          rsum[r] += p;
          plds[w][m][(lg * 4 + r) * 68 + n * 16 + lr] = f2b(p);
        }
#pragma unroll
      for (int off = 1; off < 16; off <<= 1)
#pragma unroll
        for (int r = 0; r < 4; ++r)
          rsum[r] += __shfl_xor(rsum[r], off, 64);
#pragma unroll
      for (int r = 0; r < 4; ++r)
        l_run[m][r] = l_run[m][r] * alpha[r] + rsum[r];
#pragma unroll
      for (int nd = 0; nd < 8; ++nd)
#pragma unroll
        for (int r = 0; r < 4; ++r)
          acc[m][nd][r] *= alpha[r];
    }

    // O += P * V  (P A-frags from per-wave LDS; V^T B-frags direct from global)
#pragma unroll
    for (int kk2 = 0; kk2 < 2; ++kk2) {
      bf16x8 vf[8];
#pragma unroll
      for (int nd = 0; nd < 8; ++nd)
        vf[nd] = *(const bf16x8*)&Vt[(size_t)(g * HD + nd * 16 + lr) * SEQ + kv0 + kk2 * 32 + lg * 8];
      bf16x8 pf[2];
#pragma unroll
      for (int m = 0; m < 2; ++m)
        pf[m] = *(const bf16x8*)&plds[w][m][lr * 68 + kk2 * 32 + lg * 8];
#pragma unroll
      for (int m = 0; m < 2; ++m) {
        if (!act[m]) continue;
#pragma unroll
        for (int nd = 0; nd < 8; ++nd)
          acc[m][nd] = __builtin_amdgcn_mfma_f32_16x16x32_bf16(pf[m], vf[nd], acc[m][nd], 0, 0, 0);
      }
    }
  }

#pragma unroll
  for (int m = 0; m < 2; ++m)
#pragma unroll
    for (int nd = 0; nd < 8; ++nd)
#pragma unroll
      for (int r = 0; r < 4; ++r) {
        int qrow = rw + m * 16 + lg * 4 + r;
        int col = h * HD + nd * 16 + lr;
        ctx[(size_t)qrow * DM + col] = f2b(acc[m][nd][r] / l_run[m][r]);
      }
}

extern "C" void kernel_launch(void* const* d_in, const int* in_sizes, int n_in,
                              void* d_out, int out_size, void* d_ws, size_t ws_size,
                              hipStream_t stream) {
  const float* x  = (const float*)d_in[0];
  const float* Wq = (const float*)d_in[1];
  const float* Wk = (const float*)d_in[2];
  const float* Wv = (const float*)d_in[3];
  const float* Wo = (const float*)d_in[4];
  const float* bo = (const float*)d_in[5];
  float* out = (float*)d_out;

  char* p = (char*)d_ws;
  bf16_t* xb   = (bf16_t*)p;                          // also reused as ctx later
  bf16_t* ctx  = xb;                                  // xb dead after KV GEMM
  p += (size_t)SEQ * DM * 2;                          // 16.8 MB
  bf16_t* Wqt  = (bf16_t*)p; p += (size_t)DM * DM * 2;        // 8.4 MB
  bf16_t* Wkvt = (bf16_t*)p; p += (size_t)1024 * DM * 2;      // 4.2 MB
  bf16_t* Wot  = (bf16_t*)p; p += (size_t)DM * DM * 2;        // 8.4 MB
  bf16_t* Qb   = (bf16_t*)p; p += (size_t)SEQ * DM * 2;       // 16.8 MB
  bf16_t* KVb  = (bf16_t*)p; p += (size_t)SEQ * 1024 * 2;     // 8.4 MB
  bf16_t* Vt   = (bf16_t*)p; p += (size_t)512 * SEQ * 2;      // 4.2 MB
  float*  ctab = (float*)p;  p += (size_t)SEQ * 64 * 4;       // 1 MB
  float*  stab = (float*)p;  p += (size_t)SEQ * 64 * 4;       // 1 MB

  // 1. casts / transposes
  cast_x_bf16<<<(SEQ * DM / 4 + 255) / 256, 256, 0, stream>>>(x, xb, SEQ * DM / 4);
  transpose_cast_w<<<dim3(DM / 32, DM / 32), dim3(32, 8), 0, stream>>>(Wq, Wqt, DM, DM);
  transpose_cast_w<<<dim3(512 / 32, DM / 32), dim3(32, 8), 0, stream>>>(Wk, Wkvt, DM, 512);
  transpose_cast_w<<<dim3(512 / 32, DM / 32), dim3(32, 8), 0, stream>>>(Wv, Wkvt + (size_t)512 * DM, DM, 512);
  transpose_cast_w<<<dim3(DM / 32, DM / 32), dim3(32, 8), 0, stream>>>(Wo, Wot, DM, DM);
  rope_tab<<<(SEQ * 64 + 255) / 256, 256, 0, stream>>>(ctab, stab);

  // 2. projections
  gemm_bt<0><<<dim3(DM / 128, SEQ / 128), 256, 0, stream>>>(xb, Wqt, Qb, nullptr, SEQ, DM, DM);
  gemm_bt<0><<<dim3(1024 / 128, SEQ / 128), 256, 0, stream>>>(xb, Wkvt, KVb, nullptr, SEQ, 1024, DM);

  // 3. RoPE + V transpose
  rope_apply<<<(SEQ * (NH + KVH) * 64 + 255) / 256, 256, 0, stream>>>(Qb, KVb, ctab, stab);
  transpose_v<<<dim3(512 / 32, SEQ / 32), dim3(32, 8), 0, stream>>>(KVb, Vt);

  // 4. attention (ctx aliases xb region — xb no longer needed)
  attn_fwd<<<dim3(SEQ / QBLK, NH), 256, 0, stream>>>(Qb, KVb, Vt, ctx);

  // 5. output projection + bias
  gemm_bt<1><<<dim3(DM / 128, SEQ / 128), 256, 0, stream>>>(ctx, Wot, out, bo, SEQ, DM, DM);
}

// Round 3
// 312.360 us; speedup vs baseline: 1.6732x; 1.6732x over previous
//
#include <hip/hip_runtime.h>
#include <cstdint>
#include <cstddef>

#define SEQ 4096
#define DM  2048
#define NH  16
#define KVH 4
#define HD  128

typedef short bf16_t;
typedef __attribute__((ext_vector_type(8))) short bf16x8;
typedef __attribute__((ext_vector_type(4))) float f32x4;

__device__ __forceinline__ bf16_t f2b(float f) {
  unsigned u = __builtin_bit_cast(unsigned, f);
  u += 0x7fffu + ((u >> 16) & 1u);          // RNE
  return (bf16_t)(u >> 16);
}
__device__ __forceinline__ float b2f(bf16_t s) {
  unsigned u = ((unsigned)(unsigned short)s) << 16;
  return __builtin_bit_cast(float, u);
}

// async global->LDS, 16B per lane. LDS dest is wave-uniform base + lane*16
// (linear); swizzling is done by permuting the per-lane GLOBAL source.
__device__ __forceinline__ void gload_lds16(const void* gsrc, void* ldst) {
  __builtin_amdgcn_global_load_lds(
      (__attribute__((address_space(1))) void*)gsrc,
      (__attribute__((address_space(3))) void*)ldst, 16, 0, 0);
}

// ---------------- cast x -> bf16 ----------------
__global__ void cast_x_bf16(const float* __restrict__ x, bf16_t* __restrict__ xb, int n4) {
  int i = blockIdx.x * 256 + threadIdx.x;
  if (i >= n4) return;
  float4 v = ((const float4*)x)[i];
  union { bf16_t h[4]; unsigned long long u; } o;
  o.h[0] = f2b(v.x); o.h[1] = f2b(v.y); o.h[2] = f2b(v.z); o.h[3] = f2b(v.w);
  ((unsigned long long*)xb)[i] = o.u;
}

// ---------------- W [K][N] fp32 -> Wt [N][K] bf16 ----------------
__global__ void transpose_cast_w(const float* __restrict__ W, bf16_t* __restrict__ Wt,
                                 int K, int N) {
  __shared__ float tile[32][33];
  int k0 = blockIdx.y * 32, n0 = blockIdx.x * 32;
  int tx = threadIdx.x, ty = threadIdx.y;
#pragma unroll
  for (int dy = 0; dy < 32; dy += 8)
    tile[ty + dy][tx] = W[(size_t)(k0 + ty + dy) * N + n0 + tx];
  __syncthreads();
#pragma unroll
  for (int dy = 0; dy < 32; dy += 8)
    Wt[(size_t)(n0 + ty + dy) * K + k0 + tx] = f2b(tile[tx][ty + dy]);
}

// ---------------- RoPE cos/sin table ----------------
__global__ void rope_tab(float* __restrict__ ct, float* __restrict__ st) {
  int i = blockIdx.x * 256 + threadIdx.x;
  if (i >= SEQ * 64) return;
  int t = i >> 6, j = i & 63;
  float invf = expf(-(float)j * (9.210340371976184f / 64.0f)); // 10000^(-j/64)
  float ang = (float)t * invf;
  ct[i] = cosf(ang);
  st[i] = sinf(ang);
}

// ---------------- in-place RoPE on bf16 Q and K ----------------
__global__ void rope_apply(bf16_t* __restrict__ Qb, bf16_t* __restrict__ KVb,
                           const float* __restrict__ ct, const float* __restrict__ st) {
  int i = blockIdx.x * 256 + threadIdx.x;
  const int qtot = SEQ * NH * 64;
  const int tot = qtot + SEQ * KVH * 64;
  if (i >= tot) return;
  bf16_t* base; int t, j;
  if (i < qtot) {
    t = i >> 10; int rem = i & 1023; int hh = rem >> 6; j = rem & 63;
    base = Qb + (size_t)t * DM + hh * HD;
  } else {
    int i2 = i - qtot;
    t = i2 >> 8; int rem = i2 & 255; int hh = rem >> 6; j = rem & 63;
    base = KVb + (size_t)t * 1024 + hh * HD;   // K half = cols 0..511
  }
  float c = ct[t * 64 + j], s = st[t * 64 + j];
  float x0 = b2f(base[j]);
  float x1 = b2f(base[j + 64]);
  base[j]      = f2b(x0 * c - x1 * s);
  base[j + 64] = f2b(x1 * c + x0 * s);
}

// ---------------- V half of KVb [T][1024] -> Vt [512][T] ----------------
__global__ void transpose_v(const bf16_t* __restrict__ KVb, bf16_t* __restrict__ Vt) {
  __shared__ bf16_t tile[32][33];
  int t0 = blockIdx.y * 32, d0 = blockIdx.x * 32;
  int tx = threadIdx.x, ty = threadIdx.y;
#pragma unroll
  for (int dy = 0; dy < 32; dy += 8)
    tile[ty + dy][tx] = KVb[(size_t)(t0 + ty + dy) * 1024 + 512 + d0 + tx];
  __syncthreads();
#pragma unroll
  for (int dy = 0; dy < 32; dy += 8)
    Vt[(size_t)(d0 + ty + dy) * SEQ + t0 + tx] = tile[tx][ty + dy];
}

// ---------------- GEMM: C[M][N] = A[M][K] * Bt[N][K]^T (+bias) ----------------
template <int BIAS>
__global__ __launch_bounds__(256, 2)
void gemm_bt(const bf16_t* __restrict__ A, const bf16_t* __restrict__ Bt,
             void* __restrict__ Cout, const float* __restrict__ bias,
             int M, int N, int K) {
  __shared__ __align__(16) bf16_t ldsA[128 * 64];
  __shared__ __align__(16) bf16_t ldsB[128 * 64];
  const int t = threadIdx.x;
  const int w = t >> 6, l = t & 63;
  const int lg = l >> 4, lr = l & 15;
  const int bm = blockIdx.y, bn = blockIdx.x;
  const int wr = (w >> 1) * 64, wc = (w & 1) * 64;

  f32x4 acc[4][4] = {};

  for (int k0 = 0; k0 < K; k0 += 64) {
    __syncthreads();
#pragma unroll
    for (int i = 0; i < 4; ++i) {
      int idx = i * 256 + t;          // 0..1023, 16B granules
      int row = idx >> 3;             // 8 chunks per 64-col row
      int ch  = (idx & 7) ^ (row & 7);
      gload_lds16(A  + (size_t)(bm * 128 + row) * K + k0 + ch * 8, &ldsA[idx * 8]);
      gload_lds16(Bt + (size_t)(bn * 128 + row) * K + k0 + ch * 8, &ldsB[idx * 8]);
    }
    __syncthreads();
#pragma unroll
    for (int kk = 0; kk < 2; ++kk) {
      bf16x8 af[4], bfr[4];
#pragma unroll
      for (int m = 0; m < 4; ++m) {
        int row = wr + m * 16 + lr;
        int ch = (kk * 4 + lg) ^ (row & 7);
        af[m] = *(const bf16x8*)&ldsA[row * 64 + ch * 8];
      }
#pragma unroll
      for (int n = 0; n < 4; ++n) {
        int row = wc + n * 16 + lr;
        int ch = (kk * 4 + lg) ^ (row & 7);
        bfr[n] = *(const bf16x8*)&ldsB[row * 64 + ch * 8];
      }
#pragma unroll
      for (int m = 0; m < 4; ++m)
#pragma unroll
        for (int n = 0; n < 4; ++n)
          acc[m][n] = __builtin_amdgcn_mfma_f32_16x16x32_bf16(af[m], bfr[n], acc[m][n], 0, 0, 0);
    }
  }

  // D layout: col = lane&15, row = (lane>>4)*4 + r  [measured m89]
  const int row0 = bm * 128 + wr + lg * 4;
  const int col0 = bn * 128 + wc + lr;
  if (BIAS) {
    float* C = (float*)Cout;
#pragma unroll
    for (int n = 0; n < 4; ++n) {
      int col = col0 + n * 16;
      float b = bias[col];
#pragma unroll
      for (int m = 0; m < 4; ++m)
#pragma unroll
        for (int r = 0; r < 4; ++r)
          C[(size_t)(row0 + m * 16 + r) * N + col] = acc[m][n][r] + b;
    }
  } else {
    bf16_t* C = (bf16_t*)Cout;
#pragma unroll
    for (int m = 0; m < 4; ++m)
#pragma unroll
      for (int n = 0; n < 4; ++n) {
        int col = col0 + n * 16;
#pragma unroll
        for (int r = 0; r < 4; ++r)
          C[(size_t)(row0 + m * 16 + r) * N + col] = f2b(acc[m][n][r]);
      }
  }
}

// ---------------- causal flash attention ----------------
// Paired q-tiles (b, 63-b): uniform 65 tile-computes per block. 4 waves,
// 16 q-rows/wave/tile. K+V double-buffered LDS, single barrier per KV tile.
// Row-sums via MFMA ones-column (acc[.][8]); defer-max rescale (THR=60).
__global__ __launch_bounds__(256, 2)
void attn_fwd(const bf16_t* __restrict__ Qb, const bf16_t* __restrict__ KVb,
              const bf16_t* __restrict__ Vt, bf16_t* __restrict__ ctx) {
  __shared__ __align__(16) bf16_t kt[2][64 * 128];     // K tiles, XOR-swizzled
  __shared__ __align__(16) bf16_t vts[2][128 * 64];    // V^T tiles, XOR-swizzled
  __shared__ __align__(16) bf16_t plds[4][2][16 * 64]; // per-wave per-qtile P

  const int t = threadIdx.x;
  const int w = t >> 6, l = t & 63;
  const int lg = l >> 4, lr = l & 15;
  const int h = blockIdx.y, g = h >> 2;
  const int b = blockIdx.x;
  const int qt0 = b, qt1 = 63 - b;          // light / heavy q-tiles

  // Q fragments (A-operand: row = lane&15, k = (lane>>4)*8+i)
  bf16x8 qf[2][4];
#pragma unroll
  for (int kk = 0; kk < 4; ++kk) {
    qf[0][kk] = *(const bf16x8*)&Qb[(size_t)(qt0 * 64 + w * 16 + lr) * DM + h * HD + kk * 32 + lg * 8];
    qf[1][kk] = *(const bf16x8*)&Qb[(size_t)(qt1 * 64 + w * 16 + lr) * DM + h * HD + kk * 32 + lg * 8];
  }

  f32x4 acc[2][9] = {};                     // [..][8] = row-sum (ones column)
  float m_run[2][4];
#pragma unroll
  for (int m = 0; m < 2; ++m)
#pragma unroll
    for (int r = 0; r < 4; ++r) m_run[m][r] = -1e30f;

  bf16x8 ones;
#pragma unroll
  for (int i = 0; i < 8; ++i) ones[i] = (short)0x3F80;  // bf16 1.0

  const float sl2e = 0.08838834764831845f * 1.4426950408889634f; // scale*log2(e)

  const bf16_t* ksrc = KVb + g * 128;
  const bf16_t* vsrc = Vt + (size_t)(g * 128) * SEQ;
  auto stage = [&](int buf, int kvt) {
#pragma unroll
    for (int i = 0; i < 4; ++i) {           // K [64][128]: 16 chunks/row
      int idx = i * 256 + t;
      int row = idx >> 4;
      int ch = (idx & 15) ^ (row & 7);
      gload_lds16(ksrc + (size_t)(kvt * 64 + row) * 1024 + ch * 8, &kt[buf][idx * 8]);
    }
#pragma unroll
    for (int i = 0; i < 4; ++i) {           // V^T [128][64]: 8 chunks/row
      int idx = i * 256 + t;
      int row = idx >> 3;
      int ch = (idx & 7) ^ (row & 7);
      gload_lds16(vsrc + (size_t)row * SEQ + kvt * 64 + ch * 8, &vts[buf][idx * 8]);
    }
  };

  const int nkv = qt1 + 1;
  stage(0, 0);

  for (int kv = 0; kv < nkv; ++kv) {
    const int cur = kv & 1;
    const int kv0 = kv * 64;
    __syncthreads();                        // kt/vts[cur] ready (vmcnt drained)
    if (kv + 1 < nkv) stage(cur ^ 1, kv + 1);

    const bool act0 = kv <= qt0;            // heavy tile always active

    // S = Q K^T, K-frags shared between both q-tiles
    f32x4 s[2][4];
#pragma unroll
    for (int m = 0; m < 2; ++m)
#pragma unroll
      for (int n = 0; n < 4; ++n) s[m][n] = f32x4{0.f, 0.f, 0.f, 0.f};

    __builtin_amdgcn_s_setprio(1);
#pragma unroll
    for (int n = 0; n < 4; ++n) {
      int row = n * 16 + lr;
#pragma unroll
      for (int kk = 0; kk < 4; ++kk) {
        int ch = (kk * 4 + lg) ^ (row & 7);
        bf16x8 kf = *(const bf16x8*)&kt[cur][row * 128 + ch * 8];
        if (act0) s[0][n] = __builtin_amdgcn_mfma_f32_16x16x32_bf16(qf[0][kk], kf, s[0][n], 0, 0, 0);
        s[1][n] = __builtin_amdgcn_mfma_f32_16x16x32_bf16(qf[1][kk], kf, s[1][n], 0, 0, 0);
      }
    }
    __builtin_amdgcn_s_setprio(0);

    // softmax per q-tile
#pragma unroll
    for (int m = 0; m < 2; ++m) {
      if (m == 0 && !act0) continue;
      const int qtm = (m == 0) ? qt0 : qt1;

      if (kv == qtm) {                      // diagonal tile: causal mask
#pragma unroll
        for (int n = 0; n < 4; ++n)
#pragma unroll
          for (int r = 0; r < 4; ++r) {
            int key = kv0 + n * 16 + lr;
            int qrow = qtm * 64 + w * 16 + lg * 4 + r;
            if (key > qrow) s[m][n][r] = -1e30f;
          }
      }

      float pmax[4];
#pragma unroll
      for (int r = 0; r < 4; ++r)
        pmax[r] = fmaxf(fmaxf(s[m][0][r], s[m][1][r]), fmaxf(s[m][2][r], s[m][3][r]));
#pragma unroll
      for (int off = 1; off < 16; off <<= 1)
#pragma unroll
        for (int r = 0; r < 4; ++r)
          pmax[r] = fmaxf(pmax[r], __shfl_xor(pmax[r], off, 64));

      // defer-max: rescale only when the running max grew materially
      bool need = false;
#pragma unroll
      for (int r = 0; r < 4; ++r) need |= (pmax[r] > m_run[m][r] + 60.f);
      if (__any((int)need)) {
        float alpha[4];
#pragma unroll
        for (int r = 0; r < 4; ++r) {
          float mn = fmaxf(m_run[m][r], pmax[r]);
          alpha[r] = exp2f((m_run[m][r] - mn) * sl2e);
          m_run[m][r] = mn;
        }
#pragma unroll
        for (int nd = 0; nd < 9; ++nd)
#pragma unroll
          for (int r = 0; r < 4; ++r)
            acc[m][nd][r] *= alpha[r];
      }

#pragma unroll
      for (int n = 0; n < 4; ++n)
#pragma unroll
        for (int r = 0; r < 4; ++r) {
          float p = exp2f((s[m][n][r] - m_run[m][r]) * sl2e);
          int row = lg * 4 + r;             // D-layout -> P lds (XOR-swizzled)
          int col = n * 16 + lr;
          int ch = (col >> 3) ^ (row & 7);
          plds[w][m][row * 64 + ch * 8 + (col & 7)] = f2b(p);
        }
    }

    // O += P * V; row-sum via ones column. V-frags shared between q-tiles.
#pragma unroll
    for (int kk2 = 0; kk2 < 2; ++kk2) {
      int pch = (kk2 * 4 + lg) ^ (lr & 7);
      bf16x8 pf0 = *(const bf16x8*)&plds[w][0][lr * 64 + pch * 8];
      bf16x8 pf1 = *(const bf16x8*)&plds[w][1][lr * 64 + pch * 8];
      __builtin_amdgcn_s_setprio(1);
#pragma unroll
      for (int nd = 0; nd < 8; ++nd) {
        int vrow = nd * 16 + lr;
        int vch = (kk2 * 4 + lg) ^ (vrow & 7);
        bf16x8 vf = *(const bf16x8*)&vts[cur][vrow * 64 + vch * 8];
        if (act0) acc[0][nd] = __builtin_amdgcn_mfma_f32_16x16x32_bf16(pf0, vf, acc[0][nd], 0, 0, 0);
        acc[1][nd] = __builtin_amdgcn_mfma_f32_16x16x32_bf16(pf1, vf, acc[1][nd], 0, 0, 0);
      }
      if (act0) acc[0][8] = __builtin_amdgcn_mfma_f32_16x16x32_bf16(pf0, ones, acc[0][8], 0, 0, 0);
      acc[1][8] = __builtin_amdgcn_mfma_f32_16x16x32_bf16(pf1, ones, acc[1][8], 0, 0, 0);
      __builtin_amdgcn_s_setprio(0);
    }
  }

#pragma unroll
  for (int m = 0; m < 2; ++m) {
    const int qtm = (m == 0) ? qt0 : qt1;
#pragma unroll
    for (int r = 0; r < 4; ++r) {
      float rl = 1.0f / acc[m][8][r];
      int qrow = qtm * 64 + w * 16 + lg * 4 + r;
#pragma unroll
      for (int nd = 0; nd < 8; ++nd) {
        int col = h * HD + nd * 16 + lr;
        ctx[(size_t)qrow * DM + col] = f2b(acc[m][nd][r] * rl);
      }
    }
  }
}

extern "C" void kernel_launch(void* const* d_in, const int* in_sizes, int n_in,
                              void* d_out, int out_size, void* d_ws, size_t ws_size,
                              hipStream_t stream) {
  const float* x  = (const float*)d_in[0];
  const float* Wq = (const float*)d_in[1];
  const float* Wk = (const float*)d_in[2];
  const float* Wv = (const float*)d_in[3];
  const float* Wo = (const float*)d_in[4];
  const float* bo = (const float*)d_in[5];
  float* out = (float*)d_out;

  char* p = (char*)d_ws;
  bf16_t* xb   = (bf16_t*)p;                          // also reused as ctx later
  bf16_t* ctx  = xb;                                  // xb dead after KV GEMM
  p += (size_t)SEQ * DM * 2;                          // 16.8 MB
  bf16_t* Wqt  = (bf16_t*)p; p += (size_t)DM * DM * 2;        // 8.4 MB
  bf16_t* Wkvt = (bf16_t*)p; p += (size_t)1024 * DM * 2;      // 4.2 MB
  bf16_t* Wot  = (bf16_t*)p; p += (size_t)DM * DM * 2;        // 8.4 MB
  bf16_t* Qb   = (bf16_t*)p; p += (size_t)SEQ * DM * 2;       // 16.8 MB
  bf16_t* KVb  = (bf16_t*)p; p += (size_t)SEQ * 1024 * 2;     // 8.4 MB
  bf16_t* Vt   = (bf16_t*)p; p += (size_t)512 * SEQ * 2;      // 4.2 MB
  float*  ctab = (float*)p;  p += (size_t)SEQ * 64 * 4;       // 1 MB
  float*  stab = (float*)p;  p += (size_t)SEQ * 64 * 4;       // 1 MB

  // 1. casts / transposes
  cast_x_bf16<<<(SEQ * DM / 4 + 255) / 256, 256, 0, stream>>>(x, xb, SEQ * DM / 4);
  transpose_cast_w<<<dim3(DM / 32, DM / 32), dim3(32, 8), 0, stream>>>(Wq, Wqt, DM, DM);
  transpose_cast_w<<<dim3(512 / 32, DM / 32), dim3(32, 8), 0, stream>>>(Wk, Wkvt, DM, 512);
  transpose_cast_w<<<dim3(512 / 32, DM / 32), dim3(32, 8), 0, stream>>>(Wv, Wkvt + (size_t)512 * DM, DM, 512);
  transpose_cast_w<<<dim3(DM / 32, DM / 32), dim3(32, 8), 0, stream>>>(Wo, Wot, DM, DM);
  rope_tab<<<(SEQ * 64 + 255) / 256, 256, 0, stream>>>(ctab, stab);

  // 2. projections
  gemm_bt<0><<<dim3(DM / 128, SEQ / 128), 256, 0, stream>>>(xb, Wqt, Qb, nullptr, SEQ, DM, DM);
  gemm_bt<0><<<dim3(1024 / 128, SEQ / 128), 256, 0, stream>>>(xb, Wkvt, KVb, nullptr, SEQ, 1024, DM);

  // 3. RoPE + V transpose
  rope_apply<<<(SEQ * (NH + KVH) * 64 + 255) / 256, 256, 0, stream>>>(Qb, KVb, ctab, stab);
  transpose_v<<<dim3(512 / 32, SEQ / 32), dim3(32, 8), 0, stream>>>(KVb, Vt);

  // 4. attention (ctx aliases xb region — xb no longer needed)
  attn_fwd<<<dim3(32, NH), 256, 0, stream>>>(Qb, KVb, Vt, ctx);

  // 5. output projection + bias
  gemm_bt<1><<<dim3(DM / 128, SEQ / 128), 256, 0, stream>>>(ctx, Wot, out, bo, SEQ, DM, DM);
}

// Round 4
// 299.871 us; speedup vs baseline: 1.7429x; 1.0416x over previous
//
#include <hip/hip_runtime.h>
#include <cstdint>
#include <cstddef>

#define SEQ 4096
#define DM  2048
#define NH  16
#define KVH 4
#define HD  128

typedef short bf16_t;
typedef __attribute__((ext_vector_type(8))) short bf16x8;
typedef __attribute__((ext_vector_type(4))) float f32x4;

__device__ __forceinline__ bf16_t f2b(float f) {
  unsigned u = __builtin_bit_cast(unsigned, f);
  u += 0x7fffu + ((u >> 16) & 1u);          // RNE
  return (bf16_t)(u >> 16);
}
__device__ __forceinline__ float b2f(bf16_t s) {
  unsigned u = ((unsigned)(unsigned short)s) << 16;
  return __builtin_bit_cast(float, u);
}

// async global->LDS, 16B per lane. LDS dest is wave-uniform base + lane*16
// (linear); swizzling is done by permuting the per-lane GLOBAL source.
__device__ __forceinline__ void gload_lds16(const void* gsrc, void* ldst) {
  __builtin_amdgcn_global_load_lds(
      (__attribute__((address_space(1))) void*)gsrc,
      (__attribute__((address_space(3))) void*)ldst, 16, 0, 0);
}

// ---------------- cast x -> bf16 ----------------
__global__ void cast_x_bf16(const float* __restrict__ x, bf16_t* __restrict__ xb, int n4) {
  int i = blockIdx.x * 256 + threadIdx.x;
  if (i >= n4) return;
  float4 v = ((const float4*)x)[i];
  union { bf16_t h[4]; unsigned long long u; } o;
  o.h[0] = f2b(v.x); o.h[1] = f2b(v.y); o.h[2] = f2b(v.z); o.h[3] = f2b(v.w);
  ((unsigned long long*)xb)[i] = o.u;
}

// ---------------- W [K][N] fp32 -> Wt [N][K] bf16 ----------------
__global__ void transpose_cast_w(const float* __restrict__ W, bf16_t* __restrict__ Wt,
                                 int K, int N) {
  __shared__ float tile[32][33];
  int k0 = blockIdx.y * 32, n0 = blockIdx.x * 32;
  int tx = threadIdx.x, ty = threadIdx.y;
#pragma unroll
  for (int dy = 0; dy < 32; dy += 8)
    tile[ty + dy][tx] = W[(size_t)(k0 + ty + dy) * N + n0 + tx];
  __syncthreads();
#pragma unroll
  for (int dy = 0; dy < 32; dy += 8)
    Wt[(size_t)(n0 + ty + dy) * K + k0 + tx] = f2b(tile[tx][ty + dy]);
}

// ---------------- RoPE cos/sin table ----------------
__global__ void rope_tab(float* __restrict__ ct, float* __restrict__ st) {
  int i = blockIdx.x * 256 + threadIdx.x;
  if (i >= SEQ * 64) return;
  int t = i >> 6, j = i & 63;
  float invf = expf(-(float)j * (9.210340371976184f / 64.0f)); // 10000^(-j/64)
  float ang = (float)t * invf;
  ct[i] = cosf(ang);
  st[i] = sinf(ang);
}

// ---------------- in-place RoPE on bf16 Q and K ----------------
__global__ void rope_apply(bf16_t* __restrict__ Qb, bf16_t* __restrict__ KVb,
                           const float* __restrict__ ct, const float* __restrict__ st) {
  int i = blockIdx.x * 256 + threadIdx.x;
  const int qtot = SEQ * NH * 64;
  const int tot = qtot + SEQ * KVH * 64;
  if (i >= tot) return;
  bf16_t* base; int t, j;
  if (i < qtot) {
    t = i >> 10; int rem = i & 1023; int hh = rem >> 6; j = rem & 63;
    base = Qb + (size_t)t * DM + hh * HD;
  } else {
    int i2 = i - qtot;
    t = i2 >> 8; int rem = i2 & 255; int hh = rem >> 6; j = rem & 63;
    base = KVb + (size_t)t * 1024 + hh * HD;   // K half = cols 0..511
  }
  float c = ct[t * 64 + j], s = st[t * 64 + j];
  float x0 = b2f(base[j]);
  float x1 = b2f(base[j + 64]);
  base[j]      = f2b(x0 * c - x1 * s);
  base[j + 64] = f2b(x1 * c + x0 * s);
}

// ---------------- V half of KVb [T][1024] -> Vt [512][T] ----------------
__global__ void transpose_v(const bf16_t* __restrict__ KVb, bf16_t* __restrict__ Vt) {
  __shared__ bf16_t tile[32][33];
  int t0 = blockIdx.y * 32, d0 = blockIdx.x * 32;
  int tx = threadIdx.x, ty = threadIdx.y;
#pragma unroll
  for (int dy = 0; dy < 32; dy += 8)
    tile[ty + dy][tx] = KVb[(size_t)(t0 + ty + dy) * 1024 + 512 + d0 + tx];
  __syncthreads();
#pragma unroll
  for (int dy = 0; dy < 32; dy += 8)
    Vt[(size_t)(d0 + ty + dy) * SEQ + t0 + tx] = tile[tx][ty + dy];
}

// ---------------- GEMM: C[M][N] = A[M][K] * Bt[N][K]^T (+bias) ----------------
template <int BIAS>
__global__ __launch_bounds__(256, 2)
void gemm_bt(const bf16_t* __restrict__ A, const bf16_t* __restrict__ Bt,
             void* __restrict__ Cout, const float* __restrict__ bias,
             int M, int N, int K) {
  __shared__ __align__(16) bf16_t ldsA[128 * 64];
  __shared__ __align__(16) bf16_t ldsB[128 * 64];
  const int t = threadIdx.x;
  const int w = t >> 6, l = t & 63;
  const int lg = l >> 4, lr = l & 15;
  const int bm = blockIdx.y, bn = blockIdx.x;
  const int wr = (w >> 1) * 64, wc = (w & 1) * 64;

  f32x4 acc[4][4] = {};

  for (int k0 = 0; k0 < K; k0 += 64) {
    __syncthreads();
#pragma unroll
    for (int i = 0; i < 4; ++i) {
      int idx = i * 256 + t;          // 0..1023, 16B granules
      int row = idx >> 3;             // 8 chunks per 64-col row
      int ch  = (idx & 7) ^ (row & 7);
      gload_lds16(A  + (size_t)(bm * 128 + row) * K + k0 + ch * 8, &ldsA[idx * 8]);
      gload_lds16(Bt + (size_t)(bn * 128 + row) * K + k0 + ch * 8, &ldsB[idx * 8]);
    }
    __syncthreads();
#pragma unroll
    for (int kk = 0; kk < 2; ++kk) {
      bf16x8 af[4], bfr[4];
#pragma unroll
      for (int m = 0; m < 4; ++m) {
        int row = wr + m * 16 + lr;
        int ch = (kk * 4 + lg) ^ (row & 7);
        af[m] = *(const bf16x8*)&ldsA[row * 64 + ch * 8];
      }
#pragma unroll
      for (int n = 0; n < 4; ++n) {
        int row = wc + n * 16 + lr;
        int ch = (kk * 4 + lg) ^ (row & 7);
        bfr[n] = *(const bf16x8*)&ldsB[row * 64 + ch * 8];
      }
#pragma unroll
      for (int m = 0; m < 4; ++m)
#pragma unroll
        for (int n = 0; n < 4; ++n)
          acc[m][n] = __builtin_amdgcn_mfma_f32_16x16x32_bf16(af[m], bfr[n], acc[m][n], 0, 0, 0);
    }
  }

  // D layout: col = lane&15, row = (lane>>4)*4 + r  [measured m89]
  const int row0 = bm * 128 + wr + lg * 4;
  const int col0 = bn * 128 + wc + lr;
  if (BIAS) {
    float* C = (float*)Cout;
#pragma unroll
    for (int n = 0; n < 4; ++n) {
      int col = col0 + n * 16;
      float b = bias[col];
#pragma unroll
      for (int m = 0; m < 4; ++m)
#pragma unroll
        for (int r = 0; r < 4; ++r)
          C[(size_t)(row0 + m * 16 + r) * N + col] = acc[m][n][r] + b;
    }
  } else {
    bf16_t* C = (bf16_t*)Cout;
#pragma unroll
    for (int m = 0; m < 4; ++m)
#pragma unroll
      for (int n = 0; n < 4; ++n) {
        int col = col0 + n * 16;
#pragma unroll
        for (int r = 0; r < 4; ++r)
          C[(size_t)(row0 + m * 16 + r) * N + col] = f2b(acc[m][n][r]);
      }
  }
}

// ---------------- causal flash attention ----------------
// Paired q-tiles (b, 63-b): uniform 65 tile-computes per block. 4 waves,
// 16 q-rows/wave/tile. K+V double-buffered LDS, single barrier per KV tile.
// SWAPPED QK^T (mfma(K,Q)): lane holds S for ONE q-row (q=lane&15) x 16 keys
// -> in-lane row-max + 2 shfl; scalar m_run; P packed to u64, 4 ds_write_b64.
// Row-sums via MFMA ones-column (acc[.][8]); defer-max rescale (THR=60).
__global__ __launch_bounds__(256, 2)
void attn_fwd(const bf16_t* __restrict__ Qb, const bf16_t* __restrict__ KVb,
              const bf16_t* __restrict__ Vt, bf16_t* __restrict__ ctx) {
  __shared__ __align__(16) bf16_t kt[2][64 * 128];     // K tiles, XOR-swizzled
  __shared__ __align__(16) bf16_t vts[2][128 * 64];    // V^T tiles, XOR-swizzled
  __shared__ __align__(16) bf16_t plds[4][2][16 * 64]; // per-wave per-qtile P (granule-swz)

  const int t = threadIdx.x;
  const int w = t >> 6, l = t & 63;
  const int lg = l >> 4, lr = l & 15;
  const int h = blockIdx.y, g = h >> 2;
  const int b = blockIdx.x;
  const int qt0 = b, qt1 = 63 - b;          // light / heavy q-tiles

  // Q fragments: identical per-lane data serves as B-operand after the swap
  bf16x8 qf[2][4];
#pragma unroll
  for (int kk = 0; kk < 4; ++kk) {
    qf[0][kk] = *(const bf16x8*)&Qb[(size_t)(qt0 * 64 + w * 16 + lr) * DM + h * HD + kk * 32 + lg * 8];
    qf[1][kk] = *(const bf16x8*)&Qb[(size_t)(qt1 * 64 + w * 16 + lr) * DM + h * HD + kk * 32 + lg * 8];
  }

  f32x4 acc[2][9] = {};                     // [..][8] = row-sum (ones column)
  float m_run[2] = {-1e30f, -1e30f};        // scalar: lane's q-row = lr

  bf16x8 ones;
#pragma unroll
  for (int i = 0; i < 8; ++i) ones[i] = (short)0x3F80;  // bf16 1.0

  const float sl2e = 0.08838834764831845f * 1.4426950408889634f; // scale*log2(e)
  const int swz = (lr & 7) << 1;            // P-lds granule swizzle (keeps bit0)

  const bf16_t* ksrc = KVb + g * 128;
  const bf16_t* vsrc = Vt + (size_t)(g * 128) * SEQ;
  auto stage = [&](int buf, int kvt) {
#pragma unroll
    for (int i = 0; i < 4; ++i) {           // K [64][128]: 16 chunks/row
      int idx = i * 256 + t;
      int row = idx >> 4;
      int ch = (idx & 15) ^ (row & 7);
      gload_lds16(ksrc + (size_t)(kvt * 64 + row) * 1024 + ch * 8, &kt[buf][idx * 8]);
    }
#pragma unroll
    for (int i = 0; i < 4; ++i) {           // V^T [128][64]: 8 chunks/row
      int idx = i * 256 + t;
      int row = idx >> 3;
      int ch = (idx & 7) ^ (row & 7);
      gload_lds16(vsrc + (size_t)row * SEQ + kvt * 64 + ch * 8, &vts[buf][idx * 8]);
    }
  };

  const int nkv = qt1 + 1;
  stage(0, 0);

  for (int kv = 0; kv < nkv; ++kv) {
    const int cur = kv & 1;
    const int kv0 = kv * 64;
    __syncthreads();                        // kt/vts[cur] ready (vmcnt drained)
    if (kv + 1 < nkv) stage(cur ^ 1, kv + 1);

    const bool act0 = kv <= qt0;            // heavy tile (m=1) always active

    // S^T = K Q^T (swapped): lane holds q = lr, key = kv0 + n*16 + lg*4 + r
    f32x4 s[2][4];
#pragma unroll
    for (int m = 0; m < 2; ++m)
#pragma unroll
      for (int n = 0; n < 4; ++n) s[m][n] = f32x4{0.f, 0.f, 0.f, 0.f};

    __builtin_amdgcn_s_setprio(1);
#pragma unroll
    for (int n = 0; n < 4; ++n) {
      int row = n * 16 + lr;
#pragma unroll
      for (int kk = 0; kk < 4; ++kk) {
        int ch = (kk * 4 + lg) ^ (row & 7);
        bf16x8 kf = *(const bf16x8*)&kt[cur][row * 128 + ch * 8];
        if (act0) s[0][n] = __builtin_amdgcn_mfma_f32_16x16x32_bf16(kf, qf[0][kk], s[0][n], 0, 0, 0);
        s[1][n] = __builtin_amdgcn_mfma_f32_16x16x32_bf16(kf, qf[1][kk], s[1][n], 0, 0, 0);
      }
    }
    __builtin_amdgcn_s_setprio(0);

    // softmax per q-tile (S-domain: one q-row per lane)
#pragma unroll
    for (int m = 0; m < 2; ++m) {
      if (m == 0 && !act0) continue;
      const int qtm = (m == 0) ? qt0 : qt1;
      const int qrow = qtm * 64 + w * 16 + lr;

      if (kv == qtm) {                      // diagonal tile: causal mask
#pragma unroll
        for (int n = 0; n < 4; ++n)
#pragma unroll
          for (int r = 0; r < 4; ++r) {
            int key = kv0 + n * 16 + lg * 4 + r;
            if (key > qrow) s[m][n][r] = -1e30f;
          }
      }

      // row max: in-lane over 16 values, then across the 4 lg lanes
      float pm0 = fmaxf(fmaxf(s[m][0][0], s[m][0][1]), fmaxf(s[m][0][2], s[m][0][3]));
      float pm1 = fmaxf(fmaxf(s[m][1][0], s[m][1][1]), fmaxf(s[m][1][2], s[m][1][3]));
      float pm2 = fmaxf(fmaxf(s[m][2][0], s[m][2][1]), fmaxf(s[m][2][2], s[m][2][3]));
      float pm3 = fmaxf(fmaxf(s[m][3][0], s[m][3][1]), fmaxf(s[m][3][2], s[m][3][3]));
      float pm = fmaxf(fmaxf(pm0, pm1), fmaxf(pm2, pm3));
      pm = fmaxf(pm, __shfl_xor(pm, 16, 64));
      pm = fmaxf(pm, __shfl_xor(pm, 32, 64));

      // defer-max: rescale only when the running max grew materially
      if (__any((int)(pm > m_run[m] + 60.f))) {
        float mn = fmaxf(m_run[m], pm);
        float a_s = exp2f((m_run[m] - mn) * sl2e);
        m_run[m] = mn;
        float alpha[4];
#pragma unroll
        for (int r = 0; r < 4; ++r)         // broadcast to O-domain rows lg*4+r
          alpha[r] = __shfl(a_s, (l & 48) | (lg * 4 + r), 64);
#pragma unroll
        for (int nd = 0; nd < 9; ++nd)
#pragma unroll
          for (int r = 0; r < 4; ++r)
            acc[m][nd][r] *= alpha[r];
      }

      // P = exp2((s-m)*sl2e): 4 consecutive keys/lane per n -> one u64 write
#pragma unroll
      for (int n = 0; n < 4; ++n) {
        union { bf16_t h[4]; unsigned long long u; } pk;
#pragma unroll
        for (int r = 0; r < 4; ++r)
          pk.h[r] = f2b(exp2f((s[m][n][r] - m_run[m]) * sl2e));
        int gr = (n * 4 + lg) ^ swz;        // 8B-granule index, XOR bits 1-3
        *(unsigned long long*)&plds[w][m][lr * 64 + gr * 4] = pk.u;
      }
    }

    // O += P * V; row-sum via ones column. V-frags shared between q-tiles.
#pragma unroll
    for (int kk2 = 0; kk2 < 2; ++kk2) {
      int gg = ((kk2 * 8 + lg * 2) ^ swz);  // granule pair base (bit0=0)
      bf16x8 pf0 = *(const bf16x8*)&plds[w][0][lr * 64 + gg * 4];
      bf16x8 pf1 = *(const bf16x8*)&plds[w][1][lr * 64 + gg * 4];
      __builtin_amdgcn_s_setprio(1);
#pragma unroll
      for (int nd = 0; nd < 8; ++nd) {
        int vrow = nd * 16 + lr;
        int vch = (kk2 * 4 + lg) ^ (vrow & 7);
        bf16x8 vf = *(const bf16x8*)&vts[cur][vrow * 64 + vch * 8];
        if (act0) acc[0][nd] = __builtin_amdgcn_mfma_f32_16x16x32_bf16(pf0, vf, acc[0][nd], 0, 0, 0);
        acc[1][nd] = __builtin_amdgcn_mfma_f32_16x16x32_bf16(pf1, vf, acc[1][nd], 0, 0, 0);
      }
      if (act0) acc[0][8] = __builtin_amdgcn_mfma_f32_16x16x32_bf16(pf0, ones, acc[0][8], 0, 0, 0);
      acc[1][8] = __builtin_amdgcn_mfma_f32_16x16x32_bf16(pf1, ones, acc[1][8], 0, 0, 0);
      __builtin_amdgcn_s_setprio(0);
    }
  }

#pragma unroll
  for (int m = 0; m < 2; ++m) {
    const int qtm = (m == 0) ? qt0 : qt1;
#pragma unroll
    for (int r = 0; r < 4; ++r) {
      float rl = 1.0f / acc[m][8][r];
      int qrow = qtm * 64 + w * 16 + lg * 4 + r;
#pragma unroll
      for (int nd = 0; nd < 8; ++nd) {
        int col = h * HD + nd * 16 + lr;
        ctx[(size_t)qrow * DM + col] = f2b(acc[m][nd][r] * rl);
      }
    }
  }
}

extern "C" void kernel_launch(void* const* d_in, const int* in_sizes, int n_in,
                              void* d_out, int out_size, void* d_ws, size_t ws_size,
                              hipStream_t stream) {
  const float* x  = (const float*)d_in[0];
  const float* Wq = (const float*)d_in[1];
  const float* Wk = (const float*)d_in[2];
  const float* Wv = (const float*)d_in[3];
  const float* Wo = (const float*)d_in[4];
  const float* bo = (const float*)d_in[5];
  float* out = (float*)d_out;

  char* p = (char*)d_ws;
  bf16_t* xb   = (bf16_t*)p;                          // also reused as ctx later
  bf16_t* ctx  = xb;                                  // xb dead after KV GEMM
  p += (size_t)SEQ * DM * 2;                          // 16.8 MB
  bf16_t* Wqt  = (bf16_t*)p; p += (size_t)DM * DM * 2;        // 8.4 MB
  bf16_t* Wkvt = (bf16_t*)p; p += (size_t)1024 * DM * 2;      // 4.2 MB
  bf16_t* Wot  = (bf16_t*)p; p += (size_t)DM * DM * 2;        // 8.4 MB
  bf16_t* Qb   = (bf16_t*)p; p += (size_t)SEQ * DM * 2;       // 16.8 MB
  bf16_t* KVb  = (bf16_t*)p; p += (size_t)SEQ * 1024 * 2;     // 8.4 MB
  bf16_t* Vt   = (bf16_t*)p; p += (size_t)512 * SEQ * 2;      // 4.2 MB
  float*  ctab = (float*)p;  p += (size_t)SEQ * 64 * 4;       // 1 MB
  float*  stab = (float*)p;  p += (size_t)SEQ * 64 * 4;       // 1 MB

  // 1. casts / transposes
  cast_x_bf16<<<(SEQ * DM / 4 + 255) / 256, 256, 0, stream>>>(x, xb, SEQ * DM / 4);
  transpose_cast_w<<<dim3(DM / 32, DM / 32), dim3(32, 8), 0, stream>>>(Wq, Wqt, DM, DM);
  transpose_cast_w<<<dim3(512 / 32, DM / 32), dim3(32, 8), 0, stream>>>(Wk, Wkvt, DM, 512);
  transpose_cast_w<<<dim3(512 / 32, DM / 32), dim3(32, 8), 0, stream>>>(Wv, Wkvt + (size_t)512 * DM, DM, 512);
  transpose_cast_w<<<dim3(DM / 32, DM / 32), dim3(32, 8), 0, stream>>>(Wo, Wot, DM, DM);
  rope_tab<<<(SEQ * 64 + 255) / 256, 256, 0, stream>>>(ctab, stab);

  // 2. projections
  gemm_bt<0><<<dim3(DM / 128, SEQ / 128), 256, 0, stream>>>(xb, Wqt, Qb, nullptr, SEQ, DM, DM);
  gemm_bt<0><<<dim3(1024 / 128, SEQ / 128), 256, 0, stream>>>(xb, Wkvt, KVb, nullptr, SEQ, 1024, DM);

  // 3. RoPE + V transpose
  rope_apply<<<(SEQ * (NH + KVH) * 64 + 255) / 256, 256, 0, stream>>>(Qb, KVb, ctab, stab);
  transpose_v<<<dim3(512 / 32, SEQ / 32), dim3(32, 8), 0, stream>>>(KVb, Vt);

  // 4. attention (ctx aliases xb region — xb no longer needed)
  attn_fwd<<<dim3(32, NH), 256, 0, stream>>>(Qb, KVb, Vt, ctx);

  // 5. output projection + bias
  gemm_bt<1><<<dim3(DM / 128, SEQ / 128), 256, 0, stream>>>(ctx, Wot, out, bo, SEQ, DM, DM);
}

// Round 5
// 281.256 us; speedup vs baseline: 1.8583x; 1.0662x over previous
//
#include <hip/hip_runtime.h>
#include <cstdint>
#include <cstddef>

#define SEQ 4096
#define DM  2048
#define NH  16
#define KVH 4
#define HD  128
// softmax scale folded into Q at RoPE time: 1/sqrt(128) * log2(e)
#define QSCALE (0.08838834764831845f * 1.4426950408889634f)

typedef short bf16_t;
typedef __attribute__((ext_vector_type(8))) short bf16x8;
typedef __attribute__((ext_vector_type(4))) float f32x4;
typedef __attribute__((ext_vector_type(4))) unsigned uint32x4;

__device__ __forceinline__ bf16_t f2b(float f) {
  unsigned u = __builtin_bit_cast(unsigned, f);
  u += 0x7fffu + ((u >> 16) & 1u);          // RNE
  return (bf16_t)(u >> 16);
}
__device__ __forceinline__ float b2f(bf16_t s) {
  unsigned u = ((unsigned)(unsigned short)s) << 16;
  return __builtin_bit_cast(float, u);
}
// v_cvt_pk_bf16_f32: packs 2 f32 -> 2 bf16 (RNE) in one instr (no builtin; T12)
__device__ __forceinline__ unsigned cvtpk(float lo, float hi) {
  unsigned r;
  asm("v_cvt_pk_bf16_f32 %0, %1, %2" : "=v"(r) : "v"(lo), "v"(hi));
  return r;
}

// async global->LDS, 16B per lane. LDS dest is wave-uniform base + lane*16
// (linear); swizzling is done by permuting the per-lane GLOBAL source.
__device__ __forceinline__ void gload_lds16(const void* gsrc, void* ldst) {
  __builtin_amdgcn_global_load_lds(
      (__attribute__((address_space(1))) void*)gsrc,
      (__attribute__((address_space(3))) void*)ldst, 16, 0, 0);
}

// ---------------- cast x -> bf16 ----------------
__global__ void cast_x_bf16(const float* __restrict__ x, bf16_t* __restrict__ xb, int n4) {
  int i = blockIdx.x * 256 + threadIdx.x;
  if (i >= n4) return;
  float4 v = ((const float4*)x)[i];
  union { bf16_t h[4]; unsigned long long u; } o;
  o.h[0] = f2b(v.x); o.h[1] = f2b(v.y); o.h[2] = f2b(v.z); o.h[3] = f2b(v.w);
  ((unsigned long long*)xb)[i] = o.u;
}

// ---------------- W [K][N] fp32 -> Wt [N][K] bf16 ----------------
__global__ void transpose_cast_w(const float* __restrict__ W, bf16_t* __restrict__ Wt,
                                 int K, int N) {
  __shared__ float tile[32][33];
  int k0 = blockIdx.y * 32, n0 = blockIdx.x * 32;
  int tx = threadIdx.x, ty = threadIdx.y;
#pragma unroll
  for (int dy = 0; dy < 32; dy += 8)
    tile[ty + dy][tx] = W[(size_t)(k0 + ty + dy) * N + n0 + tx];
  __syncthreads();
#pragma unroll
  for (int dy = 0; dy < 32; dy += 8)
    Wt[(size_t)(n0 + ty + dy) * K + k0 + tx] = f2b(tile[tx][ty + dy]);
}

// ---------------- RoPE cos/sin table ----------------
__global__ void rope_tab(float* __restrict__ ct, float* __restrict__ st) {
  int i = blockIdx.x * 256 + threadIdx.x;
  if (i >= SEQ * 64) return;
  int t = i >> 6, j = i & 63;
  float invf = expf(-(float)j * (9.210340371976184f / 64.0f)); // 10000^(-j/64)
  float ang = (float)t * invf;
  ct[i] = cosf(ang);
  st[i] = sinf(ang);
}

// ---------------- in-place RoPE on bf16 Q and K (Q pre-scaled) ----------------
__global__ void rope_apply(bf16_t* __restrict__ Qb, bf16_t* __restrict__ KVb,
                           const float* __restrict__ ct, const float* __restrict__ st) {
  int i = blockIdx.x * 256 + threadIdx.x;
  const int qtot = SEQ * NH * 64;
  const int tot = qtot + SEQ * KVH * 64;
  if (i >= tot) return;
  bf16_t* base; int t, j; float scl;
  if (i < qtot) {
    t = i >> 10; int rem = i & 1023; int hh = rem >> 6; j = rem & 63;
    base = Qb + (size_t)t * DM + hh * HD;
    scl = QSCALE;                              // fold softmax scale + log2e into Q
  } else {
    int i2 = i - qtot;
    t = i2 >> 8; int rem = i2 & 255; int hh = rem >> 6; j = rem & 63;
    base = KVb + (size_t)t * 1024 + hh * HD;   // K half = cols 0..511
    scl = 1.0f;
  }
  float c = ct[t * 64 + j], s = st[t * 64 + j];
  float x0 = b2f(base[j]);
  float x1 = b2f(base[j + 64]);
  base[j]      = f2b((x0 * c - x1 * s) * scl);
  base[j + 64] = f2b((x1 * c + x0 * s) * scl);
}

// ---------------- V half of KVb [T][1024] -> Vt [512][T], key-permuted ----------------
// Column index carries pi^-1 within each 64-key block:
//   pi(32a+8lg+4h+r) = 32a+16h+4lg+r  (PV A-slot -> true key)
// so P fragments after swapped-QK^T stay lane-local (pure register pack).
__global__ void transpose_v(const bf16_t* __restrict__ KVb, bf16_t* __restrict__ Vt) {
  __shared__ bf16_t tile[32][33];
  int t0 = blockIdx.y * 32, d0 = blockIdx.x * 32;
  int tx = threadIdx.x, ty = threadIdx.y;
#pragma unroll
  for (int dy = 0; dy < 32; dy += 8)
    tile[ty + dy][tx] = KVb[(size_t)(t0 + ty + dy) * 1024 + 512 + d0 + tx];
  __syncthreads();
  int tt = t0 + tx;
  int j = (tt & ~63) | (tt & 32) | ((tt & 12) << 1) | ((tt & 16) >> 2) | (tt & 3);
#pragma unroll
  for (int dy = 0; dy < 32; dy += 8)
    Vt[(size_t)(d0 + ty + dy) * SEQ + j] = tile[tx][ty + dy];
}

// ---------------- GEMM: C[M][N] = A[M][K] * Bt[N][K]^T (+bias) ----------------
template <int BIAS>
__global__ __launch_bounds__(256, 2)
void gemm_bt(const bf16_t* __restrict__ A, const bf16_t* __restrict__ Bt,
             void* __restrict__ Cout, const float* __restrict__ bias,
             int M, int N, int K) {
  __shared__ __align__(16) bf16_t ldsA[128 * 64];
  __shared__ __align__(16) bf16_t ldsB[128 * 64];
  const int t = threadIdx.x;
  const int w = t >> 6, l = t & 63;
  const int lg = l >> 4, lr = l & 15;
  const int bm = blockIdx.y, bn = blockIdx.x;
  const int wr = (w >> 1) * 64, wc = (w & 1) * 64;

  f32x4 acc[4][4] = {};

  for (int k0 = 0; k0 < K; k0 += 64) {
    __syncthreads();
#pragma unroll
    for (int i = 0; i < 4; ++i) {
      int idx = i * 256 + t;          // 0..1023, 16B granules
      int row = idx >> 3;             // 8 chunks per 64-col row
      int ch  = (idx & 7) ^ (row & 7);
      gload_lds16(A  + (size_t)(bm * 128 + row) * K + k0 + ch * 8, &ldsA[idx * 8]);
      gload_lds16(Bt + (size_t)(bn * 128 + row) * K + k0 + ch * 8, &ldsB[idx * 8]);
    }
    __syncthreads();
#pragma unroll
    for (int kk = 0; kk < 2; ++kk) {
      bf16x8 af[4], bfr[4];
#pragma unroll
      for (int m = 0; m < 4; ++m) {
        int row = wr + m * 16 + lr;
        int ch = (kk * 4 + lg) ^ (row & 7);
        af[m] = *(const bf16x8*)&ldsA[row * 64 + ch * 8];
      }
#pragma unroll
      for (int n = 0; n < 4; ++n) {
        int row = wc + n * 16 + lr;
        int ch = (kk * 4 + lg) ^ (row & 7);
        bfr[n] = *(const bf16x8*)&ldsB[row * 64 + ch * 8];
      }
#pragma unroll
      for (int m = 0; m < 4; ++m)
#pragma unroll
        for (int n = 0; n < 4; ++n)
          acc[m][n] = __builtin_amdgcn_mfma_f32_16x16x32_bf16(af[m], bfr[n], acc[m][n], 0, 0, 0);
    }
  }

  // D layout: col = lane&15, row = (lane>>4)*4 + r  [measured m89]
  const int row0 = bm * 128 + wr + lg * 4;
  const int col0 = bn * 128 + wc + lr;
  if (BIAS) {
    float* C = (float*)Cout;
#pragma unroll
    for (int n = 0; n < 4; ++n) {
      int col = col0 + n * 16;
      float b = bias[col];
#pragma unroll
      for (int m = 0; m < 4; ++m)
#pragma unroll
        for (int r = 0; r < 4; ++r)
          C[(size_t)(row0 + m * 16 + r) * N + col] = acc[m][n][r] + b;
    }
  } else {
    bf16_t* C = (bf16_t*)Cout;
#pragma unroll
    for (int m = 0; m < 4; ++m)
#pragma unroll
      for (int n = 0; n < 4; ++n) {
        int col = col0 + n * 16;
#pragma unroll
        for (int r = 0; r < 4; ++r)
          C[(size_t)(row0 + m * 16 + r) * N + col] = f2b(acc[m][n][r]);
      }
  }
}

// ---------------- causal flash attention ----------------
// Paired q-tiles (b, 63-b): uniform work. Swapped QK^T; key-permuted V so P
// stays in registers (cvt_pk pack, zero P-LDS). K+V double-buffered, one
// barrier per KV tile. Row-sum via ones-column MFMA; defer-max (THR=8,
// scaled units — Q carries scale*log2e). softmax(m1) interleaves with PV(m0).
__global__ __launch_bounds__(256, 2)
void attn_fwd(const bf16_t* __restrict__ Qb, const bf16_t* __restrict__ KVb,
              const bf16_t* __restrict__ Vt, bf16_t* __restrict__ ctx) {
  __shared__ __align__(16) bf16_t kt[2][64 * 128];     // K tiles, XOR-swizzled
  __shared__ __align__(16) bf16_t vts[2][128 * 64];    // V^T tiles (key-permuted), swizzled

  const int t = threadIdx.x;
  const int w = t >> 6, l = t & 63;
  const int lg = l >> 4, lr = l & 15;
  const int h = blockIdx.y, g = h >> 2;
  const int b = blockIdx.x;
  const int qt0 = b, qt1 = 63 - b;          // light / heavy q-tiles

  // Q fragments (B-operand after swap; row/col = lane&15, k = (lane>>4)*8+i)
  bf16x8 qf[2][4];
#pragma unroll
  for (int kk = 0; kk < 4; ++kk) {
    qf[0][kk] = *(const bf16x8*)&Qb[(size_t)(qt0 * 64 + w * 16 + lr) * DM + h * HD + kk * 32 + lg * 8];
    qf[1][kk] = *(const bf16x8*)&Qb[(size_t)(qt1 * 64 + w * 16 + lr) * DM + h * HD + kk * 32 + lg * 8];
  }

  f32x4 acc[2][9] = {};                     // [..][8] = row-sum (ones column)
  float m_run[2] = {-1e30f, -1e30f};        // per-lane q-row = lr (scaled units)

  bf16x8 ones;
#pragma unroll
  for (int i = 0; i < 8; ++i) ones[i] = (short)0x3F80;  // bf16 1.0

  const bf16_t* ksrc = KVb + g * 128;
  const bf16_t* vsrc = Vt + (size_t)(g * 128) * SEQ;
  auto stage = [&](int buf, int kvt) {
#pragma unroll
    for (int i = 0; i < 4; ++i) {           // K [64][128]: 16 chunks/row
      int idx = i * 256 + t;
      int row = idx >> 4;
      int ch = (idx & 15) ^ (row & 7);
      gload_lds16(ksrc + (size_t)(kvt * 64 + row) * 1024 + ch * 8, &kt[buf][idx * 8]);
    }
#pragma unroll
    for (int i = 0; i < 4; ++i) {           // V^T [128][64]: 8 chunks/row
      int idx = i * 256 + t;
      int row = idx >> 3;
      int ch = (idx & 7) ^ (row & 7);
      gload_lds16(vsrc + (size_t)row * SEQ + kvt * 64 + ch * 8, &vts[buf][idx * 8]);
    }
  };

  const int nkv = qt1 + 1;
  stage(0, 0);

  for (int kv = 0; kv < nkv; ++kv) {
    const int cur = kv & 1;
    const int kv0 = kv * 64;
    __syncthreads();                        // kt/vts[cur] ready (vmcnt drained)
    if (kv + 1 < nkv) stage(cur ^ 1, kv + 1);

    const bool act0 = kv <= qt0;            // heavy tile (m=1) always active

    // S^T = K Q^T (swapped): lane holds q = lr, key = kv0 + n*16 + lg*4 + r
    f32x4 s[2][4];
#pragma unroll
    for (int m = 0; m < 2; ++m)
#pragma unroll
      for (int n = 0; n < 4; ++n) s[m][n] = f32x4{0.f, 0.f, 0.f, 0.f};

    __builtin_amdgcn_s_setprio(1);
#pragma unroll
    for (int n = 0; n < 4; ++n) {
      int row = n * 16 + lr;
#pragma unroll
      for (int kk = 0; kk < 4; ++kk) {
        int ch = (kk * 4 + lg) ^ (row & 7);
        bf16x8 kf = *(const bf16x8*)&kt[cur][row * 128 + ch * 8];
        if (act0) s[0][n] = __builtin_amdgcn_mfma_f32_16x16x32_bf16(kf, qf[0][kk], s[0][n], 0, 0, 0);
        s[1][n] = __builtin_amdgcn_mfma_f32_16x16x32_bf16(kf, qf[1][kk], s[1][n], 0, 0, 0);
      }
    }
    __builtin_amdgcn_s_setprio(0);

    // softmax: mask, in-lane max, defer-max rescale, exp2, register pack
    auto softmax = [&](f32x4 (&sv)[4], float& mr, f32x4 (&am)[9], int qtm,
                       bf16x8 (&pf)[2]) {
      const int qrow = qtm * 64 + w * 16 + lr;
      if (kv == qtm) {                      // diagonal tile: causal mask
#pragma unroll
        for (int n = 0; n < 4; ++n)
#pragma unroll
          for (int r = 0; r < 4; ++r) {
            int key = kv0 + n * 16 + lg * 4 + r;
            if (key > qrow) sv[n][r] = -1e30f;
          }
      }
      float pm = sv[0][0];
#pragma unroll
      for (int n = 0; n < 4; ++n)
#pragma unroll
        for (int r = 0; r < 4; ++r)
          pm = fmaxf(pm, sv[n][r]);
      pm = fmaxf(pm, __shfl_xor(pm, 16, 64));
      pm = fmaxf(pm, __shfl_xor(pm, 32, 64));

      if (__any((int)(pm > mr + 8.f))) {    // defer-max (T13)
        float mn = fmaxf(mr, pm);
        float a_s = exp2f(mr - mn);
        mr = mn;
        float alpha[4];
#pragma unroll
        for (int r = 0; r < 4; ++r)         // broadcast to O-domain rows lg*4+r
          alpha[r] = __shfl(a_s, (l & 48) | (lg * 4 + r), 64);
#pragma unroll
        for (int nd = 0; nd < 9; ++nd)
#pragma unroll
          for (int r = 0; r < 4; ++r)
            am[nd][r] *= alpha[r];
      }

      unsigned u[8];
#pragma unroll
      for (int n = 0; n < 4; ++n) {
        u[2 * n]     = cvtpk(exp2f(sv[n][0] - mr), exp2f(sv[n][1] - mr));
        u[2 * n + 1] = cvtpk(exp2f(sv[n][2] - mr), exp2f(sv[n][3] - mr));
      }
      pf[0] = __builtin_bit_cast(bf16x8, (uint32x4){u[0], u[1], u[2], u[3]});
      pf[1] = __builtin_bit_cast(bf16x8, (uint32x4){u[4], u[5], u[6], u[7]});
    };

    auto loadvf = [&](bf16x8 (&vf)[8], int kk2) {
#pragma unroll
      for (int nd = 0; nd < 8; ++nd) {
        int vrow = nd * 16 + lr;
        int ch = (kk2 * 4 + lg) ^ (lr & 7);
        vf[nd] = *(const bf16x8*)&vts[cur][vrow * 64 + ch * 8];
      }
    };
    auto pv = [&](const bf16x8 (&vf)[8], const bf16x8& pfk, f32x4 (&am)[9]) {
      __builtin_amdgcn_s_setprio(1);
#pragma unroll
      for (int nd = 0; nd < 8; ++nd)
        am[nd] = __builtin_amdgcn_mfma_f32_16x16x32_bf16(pfk, vf[nd], am[nd], 0, 0, 0);
      am[8] = __builtin_amdgcn_mfma_f32_16x16x32_bf16(pfk, ones, am[8], 0, 0, 0);
      __builtin_amdgcn_s_setprio(0);
    };

    bf16x8 pf0[2], pf1[2];
    if (act0) softmax(s[0], m_run[0], acc[0], qt0, pf0);
    bf16x8 vfa[8];
    loadvf(vfa, 0);
    if (act0) pv(vfa, pf0[0], acc[0]);      // MFMA(m0) ...
    softmax(s[1], m_run[1], acc[1], qt1, pf1);  // ... overlaps VALU(m1)
    pv(vfa, pf1[0], acc[1]);
    bf16x8 vfb[8];
    loadvf(vfb, 1);
    if (act0) pv(vfb, pf0[1], acc[0]);
    pv(vfb, pf1[1], acc[1]);
  }

#pragma unroll
  for (int m = 0; m < 2; ++m) {
    const int qtm = (m == 0) ? qt0 : qt1;
#pragma unroll
    for (int r = 0; r < 4; ++r) {
      float rl = 1.0f / acc[m][8][r];
      int qrow = qtm * 64 + w * 16 + lg * 4 + r;
#pragma unroll
      for (int nd = 0; nd < 8; ++nd) {
        int col = h * HD + nd * 16 + lr;
        ctx[(size_t)qrow * DM + col] = f2b(acc[m][nd][r] * rl);
      }
    }
  }
}

extern "C" void kernel_launch(void* const* d_in, const int* in_sizes, int n_in,
                              void* d_out, int out_size, void* d_ws, size_t ws_size,
                              hipStream_t stream) {
  const float* x  = (const float*)d_in[0];
  const float* Wq = (const float*)d_in[1];
  const float* Wk = (const float*)d_in[2];
  const float* Wv = (const float*)d_in[3];
  const float* Wo = (const float*)d_in[4];
  const float* bo = (const float*)d_in[5];
  float* out = (float*)d_out;

  char* p = (char*)d_ws;
  bf16_t* xb   = (bf16_t*)p;                          // also reused as ctx later
  bf16_t* ctx  = xb;                                  // xb dead after KV GEMM
  p += (size_t)SEQ * DM * 2;                          // 16.8 MB
  bf16_t* Wqt  = (bf16_t*)p; p += (size_t)DM * DM * 2;        // 8.4 MB
  bf16_t* Wkvt = (bf16_t*)p; p += (size_t)1024 * DM * 2;      // 4.2 MB
  bf16_t* Wot  = (bf16_t*)p; p += (size_t)DM * DM * 2;        // 8.4 MB
  bf16_t* Qb   = (bf16_t*)p; p += (size_t)SEQ * DM * 2;       // 16.8 MB
  bf16_t* KVb  = (bf16_t*)p; p += (size_t)SEQ * 1024 * 2;     // 8.4 MB
  bf16_t* Vt   = (bf16_t*)p; p += (size_t)512 * SEQ * 2;      // 4.2 MB
  float*  ctab = (float*)p;  p += (size_t)SEQ * 64 * 4;       // 1 MB
  float*  stab = (float*)p;  p += (size_t)SEQ * 64 * 4;       // 1 MB

  // 1. casts / transposes
  cast_x_bf16<<<(SEQ * DM / 4 + 255) / 256, 256, 0, stream>>>(x, xb, SEQ * DM / 4);
  transpose_cast_w<<<dim3(DM / 32, DM / 32), dim3(32, 8), 0, stream>>>(Wq, Wqt, DM, DM);
  transpose_cast_w<<<dim3(512 / 32, DM / 32), dim3(32, 8), 0, stream>>>(Wk, Wkvt, DM, 512);
  transpose_cast_w<<<dim3(512 / 32, DM / 32), dim3(32, 8), 0, stream>>>(Wv, Wkvt + (size_t)512 * DM, DM, 512);
  transpose_cast_w<<<dim3(DM / 32, DM / 32), dim3(32, 8), 0, stream>>>(Wo, Wot, DM, DM);
  rope_tab<<<(SEQ * 64 + 255) / 256, 256, 0, stream>>>(ctab, stab);

  // 2. projections
  gemm_bt<0><<<dim3(DM / 128, SEQ / 128), 256, 0, stream>>>(xb, Wqt, Qb, nullptr, SEQ, DM, DM);
  gemm_bt<0><<<dim3(1024 / 128, SEQ / 128), 256, 0, stream>>>(xb, Wkvt, KVb, nullptr, SEQ, 1024, DM);

  // 3. RoPE + V transpose (key-permuted layout)
  rope_apply<<<(SEQ * (NH + KVH) * 64 + 255) / 256, 256, 0, stream>>>(Qb, KVb, ctab, stab);
  transpose_v<<<dim3(512 / 32, SEQ / 32), dim3(32, 8), 0, stream>>>(KVb, Vt);

  // 4. attention (ctx aliases xb region — xb no longer needed)
  attn_fwd<<<dim3(32, NH), 256, 0, stream>>>(Qb, KVb, Vt, ctx);

  // 5. output projection + bias
  gemm_bt<1><<<dim3(DM / 128, SEQ / 128), 256, 0, stream>>>(ctx, Wot, out, bo, SEQ, DM, DM);
}

// Round 6
// 275.367 us; speedup vs baseline: 1.8980x; 1.0214x over previous
//
#include <hip/hip_runtime.h>
#include <cstdint>
#include <cstddef>

#define SEQ 4096
#define DM  2048
#define NH  16
#define KVH 4
#define HD  128
// softmax scale folded into Q at RoPE time: 1/sqrt(128) * log2(e)
#define QSCALE (0.08838834764831845f * 1.4426950408889634f)

typedef short bf16_t;
typedef __attribute__((ext_vector_type(8))) short bf16x8;
typedef __attribute__((ext_vector_type(4))) float f32x4;
typedef __attribute__((ext_vector_type(4))) unsigned uint32x4;

__device__ __forceinline__ bf16_t f2b(float f) {
  unsigned u = __builtin_bit_cast(unsigned, f);
  u += 0x7fffu + ((u >> 16) & 1u);          // RNE
  return (bf16_t)(u >> 16);
}
__device__ __forceinline__ float b2f(bf16_t s) {
  unsigned u = ((unsigned)(unsigned short)s) << 16;
  return __builtin_bit_cast(float, u);
}
// v_cvt_pk_bf16_f32: packs 2 f32 -> 2 bf16 (RNE) in one instr (no builtin; T12)
__device__ __forceinline__ unsigned cvtpk(float lo, float hi) {
  unsigned r;
  asm("v_cvt_pk_bf16_f32 %0, %1, %2" : "=v"(r) : "v"(lo), "v"(hi));
  return r;
}

// async global->LDS, 16B per lane. LDS dest is wave-uniform base + lane*16
// (linear); swizzling is done by permuting the per-lane GLOBAL source.
__device__ __forceinline__ void gload_lds16(const void* gsrc, void* ldst) {
  __builtin_amdgcn_global_load_lds(
      (__attribute__((address_space(1))) void*)gsrc,
      (__attribute__((address_space(3))) void*)ldst, 16, 0, 0);
}

// ---------------- cast x -> bf16 ----------------
__global__ void cast_x_bf16(const float* __restrict__ x, bf16_t* __restrict__ xb, int n4) {
  int i = blockIdx.x * 256 + threadIdx.x;
  if (i >= n4) return;
  float4 v = ((const float4*)x)[i];
  union { bf16_t h[4]; unsigned long long u; } o;
  o.h[0] = f2b(v.x); o.h[1] = f2b(v.y); o.h[2] = f2b(v.z); o.h[3] = f2b(v.w);
  ((unsigned long long*)xb)[i] = o.u;
}

// ---------------- W [K][N] fp32 -> Wt [N][K] bf16 ----------------
__global__ void transpose_cast_w(const float* __restrict__ W, bf16_t* __restrict__ Wt,
                                 int K, int N) {
  __shared__ float tile[32][33];
  int k0 = blockIdx.y * 32, n0 = blockIdx.x * 32;
  int tx = threadIdx.x, ty = threadIdx.y;
#pragma unroll
  for (int dy = 0; dy < 32; dy += 8)
    tile[ty + dy][tx] = W[(size_t)(k0 + ty + dy) * N + n0 + tx];
  __syncthreads();
#pragma unroll
  for (int dy = 0; dy < 32; dy += 8)
    Wt[(size_t)(n0 + ty + dy) * K + k0 + tx] = f2b(tile[tx][ty + dy]);
}

// ---------------- RoPE cos/sin table ----------------
__global__ void rope_tab(float* __restrict__ ct, float* __restrict__ st) {
  int i = blockIdx.x * 256 + threadIdx.x;
  if (i >= SEQ * 64) return;
  int t = i >> 6, j = i & 63;
  float invf = expf(-(float)j * (9.210340371976184f / 64.0f)); // 10000^(-j/64)
  float ang = (float)t * invf;
  ct[i] = cosf(ang);
  st[i] = sinf(ang);
}

// ---------------- in-place RoPE on bf16 Q and K (Q pre-scaled) ----------------
__global__ void rope_apply(bf16_t* __restrict__ Qb, bf16_t* __restrict__ KVb,
                           const float* __restrict__ ct, const float* __restrict__ st) {
  int i = blockIdx.x * 256 + threadIdx.x;
  const int qtot = SEQ * NH * 64;
  const int tot = qtot + SEQ * KVH * 64;
  if (i >= tot) return;
  bf16_t* base; int t, j; float scl;
  if (i < qtot) {
    t = i >> 10; int rem = i & 1023; int hh = rem >> 6; j = rem & 63;
    base = Qb + (size_t)t * DM + hh * HD;
    scl = QSCALE;                              // fold softmax scale + log2e into Q
  } else {
    int i2 = i - qtot;
    t = i2 >> 8; int rem = i2 & 255; int hh = rem >> 6; j = rem & 63;
    base = KVb + (size_t)t * 1024 + hh * HD;   // K half = cols 0..511
    scl = 1.0f;
  }
  float c = ct[t * 64 + j], s = st[t * 64 + j];
  float x0 = b2f(base[j]);
  float x1 = b2f(base[j + 64]);
  base[j]      = f2b((x0 * c - x1 * s) * scl);
  base[j + 64] = f2b((x1 * c + x0 * s) * scl);
}

// ---------------- V half of KVb [T][1024] -> Vt [512][T], key-permuted ----------------
// Column index carries pi^-1 within each 64-key block:
//   pi(32a+8lg+4h+r) = 32a+16h+4lg+r  (PV A-slot -> true key)
// so P fragments after swapped-QK^T stay lane-local (pure register pack).
__global__ void transpose_v(const bf16_t* __restrict__ KVb, bf16_t* __restrict__ Vt) {
  __shared__ bf16_t tile[32][33];
  int t0 = blockIdx.y * 32, d0 = blockIdx.x * 32;
  int tx = threadIdx.x, ty = threadIdx.y;
#pragma unroll
  for (int dy = 0; dy < 32; dy += 8)
    tile[ty + dy][tx] = KVb[(size_t)(t0 + ty + dy) * 1024 + 512 + d0 + tx];
  __syncthreads();
  int tt = t0 + tx;
  int j = (tt & ~63) | (tt & 32) | ((tt & 12) << 1) | ((tt & 16) >> 2) | (tt & 3);
#pragma unroll
  for (int dy = 0; dy < 32; dy += 8)
    Vt[(size_t)(d0 + ty + dy) * SEQ + j] = tile[tx][ty + dy];
}

// ---------------- GEMM: C[M][N] = A[M][K] * Bt[N][K]^T (+bias) ----------------
template <int BIAS>
__global__ __launch_bounds__(256, 2)
void gemm_bt(const bf16_t* __restrict__ A, const bf16_t* __restrict__ Bt,
             void* __restrict__ Cout, const float* __restrict__ bias,
             int M, int N, int K) {
  __shared__ __align__(16) bf16_t ldsA[128 * 64];
  __shared__ __align__(16) bf16_t ldsB[128 * 64];
  const int t = threadIdx.x;
  const int w = t >> 6, l = t & 63;
  const int lg = l >> 4, lr = l & 15;
  const int bm = blockIdx.y, bn = blockIdx.x;
  const int wr = (w >> 1) * 64, wc = (w & 1) * 64;

  f32x4 acc[4][4] = {};

  for (int k0 = 0; k0 < K; k0 += 64) {
    __syncthreads();
#pragma unroll
    for (int i = 0; i < 4; ++i) {
      int idx = i * 256 + t;          // 0..1023, 16B granules
      int row = idx >> 3;             // 8 chunks per 64-col row
      int ch  = (idx & 7) ^ (row & 7);
      gload_lds16(A  + (size_t)(bm * 128 + row) * K + k0 + ch * 8, &ldsA[idx * 8]);
      gload_lds16(Bt + (size_t)(bn * 128 + row) * K + k0 + ch * 8, &ldsB[idx * 8]);
    }
    __syncthreads();
#pragma unroll
    for (int kk = 0; kk < 2; ++kk) {
      bf16x8 af[4], bfr[4];
#pragma unroll
      for (int m = 0; m < 4; ++m) {
        int row = wr + m * 16 + lr;
        int ch = (kk * 4 + lg) ^ (row & 7);
        af[m] = *(const bf16x8*)&ldsA[row * 64 + ch * 8];
      }
#pragma unroll
      for (int n = 0; n < 4; ++n) {
        int row = wc + n * 16 + lr;
        int ch = (kk * 4 + lg) ^ (row & 7);
        bfr[n] = *(const bf16x8*)&ldsB[row * 64 + ch * 8];
      }
#pragma unroll
      for (int m = 0; m < 4; ++m)
#pragma unroll
        for (int n = 0; n < 4; ++n)
          acc[m][n] = __builtin_amdgcn_mfma_f32_16x16x32_bf16(af[m], bfr[n], acc[m][n], 0, 0, 0);
    }
  }

  // D layout: col = lane&15, row = (lane>>4)*4 + r  [measured m89]
  const int row0 = bm * 128 + wr + lg * 4;
  const int col0 = bn * 128 + wc + lr;
  if (BIAS) {
    float* C = (float*)Cout;
#pragma unroll
    for (int n = 0; n < 4; ++n) {
      int col = col0 + n * 16;
      float b = bias[col];
#pragma unroll
      for (int m = 0; m < 4; ++m)
#pragma unroll
        for (int r = 0; r < 4; ++r)
          C[(size_t)(row0 + m * 16 + r) * N + col] = acc[m][n][r] + b;
    }
  } else {
    bf16_t* C = (bf16_t*)Cout;
#pragma unroll
    for (int m = 0; m < 4; ++m)
#pragma unroll
      for (int n = 0; n < 4; ++n) {
        int col = col0 + n * 16;
#pragma unroll
        for (int r = 0; r < 4; ++r)
          C[(size_t)(row0 + m * 16 + r) * N + col] = f2b(acc[m][n][r]);
      }
  }
}

// ---------------- causal flash attention ----------------
// 8 waves / 512 threads per block; paired q-tiles (b, 63-b): waves 0-3 own
// q-tile b (16 rows each), waves 4-7 own q-tile 63-b -> 4 waves/SIMD at
// 2 blocks/CU (vs 2/SIMD before; pure occupancy change, layouts identical).
// Swapped QK^T, key-permuted V (P in registers), ones-column row-sum,
// defer-max (THR=8), K+V double-buffered LDS, one barrier per KV tile.
__global__ __launch_bounds__(512, 4)
void attn_fwd(const bf16_t* __restrict__ Qb, const bf16_t* __restrict__ KVb,
              const bf16_t* __restrict__ Vt, bf16_t* __restrict__ ctx) {
  __shared__ __align__(16) bf16_t kt[2][64 * 128];     // K tiles, XOR-swizzled
  __shared__ __align__(16) bf16_t vts[2][128 * 64];    // V^T tiles (key-permuted), swizzled

  const int t = threadIdx.x;
  const int w = t >> 6, l = t & 63;
  const int lg = l >> 4, lr = l & 15;
  const int h = blockIdx.y, g = h >> 2;
  const int b = blockIdx.x;
  const int m = w >> 2, wq = w & 3;
  const int qt = m ? 63 - b : b;            // this wave's q-tile
  const int qrow0 = qt * 64 + wq * 16;      // wave's first q-row

  // Q fragments (B-operand after swap; row/col = lane&15, k = (lane>>4)*8+i)
  bf16x8 qf[4];
#pragma unroll
  for (int kk = 0; kk < 4; ++kk)
    qf[kk] = *(const bf16x8*)&Qb[(size_t)(qrow0 + lr) * DM + h * HD + kk * 32 + lg * 8];

  f32x4 acc[9] = {};                        // [8] = row-sum (ones column)
  float m_run = -1e30f;                     // per-lane q-row = lr (scaled units)

  bf16x8 ones;
#pragma unroll
  for (int i = 0; i < 8; ++i) ones[i] = (short)0x3F80;  // bf16 1.0

  const bf16_t* ksrc = KVb + g * 128;
  const bf16_t* vsrc = Vt + (size_t)(g * 128) * SEQ;
  auto stage = [&](int buf, int kvt) {
#pragma unroll
    for (int i = 0; i < 2; ++i) {           // K [64][128]: 1024 granules, 16/row
      int idx = i * 512 + t;
      int row = idx >> 4;
      int ch = (idx & 15) ^ (row & 7);
      gload_lds16(ksrc + (size_t)(kvt * 64 + row) * 1024 + ch * 8, &kt[buf][idx * 8]);
    }
#pragma unroll
    for (int i = 0; i < 2; ++i) {           // V^T [128][64]: 1024 granules, 8/row
      int idx = i * 512 + t;
      int row = idx >> 3;
      int ch = (idx & 7) ^ (row & 7);
      gload_lds16(vsrc + (size_t)row * SEQ + kvt * 64 + ch * 8, &vts[buf][idx * 8]);
    }
  };

  const int nkv = 64 - b;                   // qt1 + 1
  stage(0, 0);

  for (int kv = 0; kv < nkv; ++kv) {
    const int cur = kv & 1;
    const int kv0 = kv * 64;
    __syncthreads();                        // kt/vts[cur] ready (vmcnt drained)
    if (kv + 1 < nkv) stage(cur ^ 1, kv + 1);

    if (kv <= qt) {                         // causal: tile active for this wave
      // S^T = K Q^T (swapped): lane holds q = lr, key = kv0 + n*16 + lg*4 + r
      f32x4 s[4] = {};
      __builtin_amdgcn_s_setprio(1);
#pragma unroll
      for (int n = 0; n < 4; ++n) {
        int row = n * 16 + lr;
#pragma unroll
        for (int kk = 0; kk < 4; ++kk) {
          int ch = (kk * 4 + lg) ^ (row & 7);
          bf16x8 kf = *(const bf16x8*)&kt[cur][row * 128 + ch * 8];
          s[n] = __builtin_amdgcn_mfma_f32_16x16x32_bf16(kf, qf[kk], s[n], 0, 0, 0);
        }
      }
      __builtin_amdgcn_s_setprio(0);

      const int qrow = qrow0 + lr;
      if (kv == qt) {                       // diagonal tile: causal mask
#pragma unroll
        for (int n = 0; n < 4; ++n)
#pragma unroll
          for (int r = 0; r < 4; ++r) {
            int key = kv0 + n * 16 + lg * 4 + r;
            if (key > qrow) s[n][r] = -1e30f;
          }
      }

      // row max: in-lane over 16, then across the 4 lg lanes (xor 16, 32)
      float pm = s[0][0];
#pragma unroll
      for (int n = 0; n < 4; ++n)
#pragma unroll
        for (int r = 0; r < 4; ++r)
          pm = fmaxf(pm, s[n][r]);
      pm = fmaxf(pm, __shfl_xor(pm, 16, 64));
      pm = fmaxf(pm, __shfl_xor(pm, 32, 64));

      if (__any((int)(pm > m_run + 8.f))) { // defer-max (T13)
        float mn = fmaxf(m_run, pm);
        float a_s = exp2f(m_run - mn);
        m_run = mn;
        float alpha[4];
#pragma unroll
        for (int r = 0; r < 4; ++r)         // broadcast to O-domain rows lg*4+r
          alpha[r] = __shfl(a_s, (l & 48) | (lg * 4 + r), 64);
#pragma unroll
        for (int nd = 0; nd < 9; ++nd)
#pragma unroll
          for (int r = 0; r < 4; ++r)
            acc[nd][r] *= alpha[r];
      }

      // P = exp2(s - m), packed to bf16 in registers (key-permuted V layout)
      unsigned u[8];
#pragma unroll
      for (int n = 0; n < 4; ++n) {
        u[2 * n]     = cvtpk(exp2f(s[n][0] - m_run), exp2f(s[n][1] - m_run));
        u[2 * n + 1] = cvtpk(exp2f(s[n][2] - m_run), exp2f(s[n][3] - m_run));
      }
      bf16x8 pf[2];
      pf[0] = __builtin_bit_cast(bf16x8, (uint32x4){u[0], u[1], u[2], u[3]});
      pf[1] = __builtin_bit_cast(bf16x8, (uint32x4){u[4], u[5], u[6], u[7]});

      // O += P * V; row-sum via ones column
      __builtin_amdgcn_s_setprio(1);
#pragma unroll
      for (int kk2 = 0; kk2 < 2; ++kk2) {
#pragma unroll
        for (int nd = 0; nd < 8; ++nd) {
          int vrow = nd * 16 + lr;
          int vch = (kk2 * 4 + lg) ^ (lr & 7);
          bf16x8 vf = *(const bf16x8*)&vts[cur][vrow * 64 + vch * 8];
          acc[nd] = __builtin_amdgcn_mfma_f32_16x16x32_bf16(pf[kk2], vf, acc[nd], 0, 0, 0);
        }
        acc[8] = __builtin_amdgcn_mfma_f32_16x16x32_bf16(pf[kk2], ones, acc[8], 0, 0, 0);
      }
      __builtin_amdgcn_s_setprio(0);
    }
  }

#pragma unroll
  for (int r = 0; r < 4; ++r) {
    float rl = 1.0f / acc[8][r];
    int qrow = qrow0 + lg * 4 + r;
#pragma unroll
    for (int nd = 0; nd < 8; ++nd) {
      int col = h * HD + nd * 16 + lr;
      ctx[(size_t)qrow * DM + col] = f2b(acc[nd][r] * rl);
    }
  }
}

extern "C" void kernel_launch(void* const* d_in, const int* in_sizes, int n_in,
                              void* d_out, int out_size, void* d_ws, size_t ws_size,
                              hipStream_t stream) {
  const float* x  = (const float*)d_in[0];
  const float* Wq = (const float*)d_in[1];
  const float* Wk = (const float*)d_in[2];
  const float* Wv = (const float*)d_in[3];
  const float* Wo = (const float*)d_in[4];
  const float* bo = (const float*)d_in[5];
  float* out = (float*)d_out;

  char* p = (char*)d_ws;
  bf16_t* xb   = (bf16_t*)p;                          // also reused as ctx later
  bf16_t* ctx  = xb;                                  // xb dead after KV GEMM
  p += (size_t)SEQ * DM * 2;                          // 16.8 MB
  bf16_t* Wqt  = (bf16_t*)p; p += (size_t)DM * DM * 2;        // 8.4 MB
  bf16_t* Wkvt = (bf16_t*)p; p += (size_t)1024 * DM * 2;      // 4.2 MB
  bf16_t* Wot  = (bf16_t*)p; p += (size_t)DM * DM * 2;        // 8.4 MB
  bf16_t* Qb   = (bf16_t*)p; p += (size_t)SEQ * DM * 2;       // 16.8 MB
  bf16_t* KVb  = (bf16_t*)p; p += (size_t)SEQ * 1024 * 2;     // 8.4 MB
  bf16_t* Vt   = (bf16_t*)p; p += (size_t)512 * SEQ * 2;      // 4.2 MB
  float*  ctab = (float*)p;  p += (size_t)SEQ * 64 * 4;       // 1 MB
  float*  stab = (float*)p;  p += (size_t)SEQ * 64 * 4;       // 1 MB

  // 1. casts / transposes
  cast_x_bf16<<<(SEQ * DM / 4 + 255) / 256, 256, 0, stream>>>(x, xb, SEQ * DM / 4);
  transpose_cast_w<<<dim3(DM / 32, DM / 32), dim3(32, 8), 0, stream>>>(Wq, Wqt, DM, DM);
  transpose_cast_w<<<dim3(512 / 32, DM / 32), dim3(32, 8), 0, stream>>>(Wk, Wkvt, DM, 512);
  transpose_cast_w<<<dim3(512 / 32, DM / 32), dim3(32, 8), 0, stream>>>(Wv, Wkvt + (size_t)512 * DM, DM, 512);
  transpose_cast_w<<<dim3(DM / 32, DM / 32), dim3(32, 8), 0, stream>>>(Wo, Wot, DM, DM);
  rope_tab<<<(SEQ * 64 + 255) / 256, 256, 0, stream>>>(ctab, stab);

  // 2. projections
  gemm_bt<0><<<dim3(DM / 128, SEQ / 128), 256, 0, stream>>>(xb, Wqt, Qb, nullptr, SEQ, DM, DM);
  gemm_bt<0><<<dim3(1024 / 128, SEQ / 128), 256, 0, stream>>>(xb, Wkvt, KVb, nullptr, SEQ, 1024, DM);

  // 3. RoPE + V transpose (key-permuted layout)
  rope_apply<<<(SEQ * (NH + KVH) * 64 + 255) / 256, 256, 0, stream>>>(Qb, KVb, ctab, stab);
  transpose_v<<<dim3(512 / 32, SEQ / 32), dim3(32, 8), 0, stream>>>(KVb, Vt);

  // 4. attention (ctx aliases xb region — xb no longer needed)
  attn_fwd<<<dim3(32, NH), 512, 0, stream>>>(Qb, KVb, Vt, ctx);

  // 5. output projection + bias
  gemm_bt<1><<<dim3(DM / 128, SEQ / 128), 256, 0, stream>>>(ctx, Wot, out, bo, SEQ, DM, DM);
}